// Round 6
// baseline (676.992 us; speedup 1.0000x reference)
//
#include <hip/hip_runtime.h>
#include <math.h>

#define BB  8
#define SEQ 2048
#define EMB 512
#define NH  8
#define DH  64
#define NBH (BB * NH)                      // 64
#define MROWS (BB * SEQ)                   // 16384
#define QKV_ELEMS ((size_t)NBH * SEQ * DH) // 8388608
#define MASK_ELEMS (BB * (SEQ - 1))        // 16376
// 512^-0.5 * log2(e): q pre-scaled so softmax uses exp2 directly
#define QSCALE 0.06375871307545f

typedef __attribute__((ext_vector_type(8)))  short short8;
typedef __attribute__((ext_vector_type(4)))  float float4e;
typedef __attribute__((ext_vector_type(16))) float float16e;
typedef __attribute__((ext_vector_type(4)))  unsigned int uint4e;
typedef __attribute__((ext_vector_type(2)))  unsigned int uint2e;
typedef unsigned short ushort_t;

static __device__ inline unsigned short f2bf(float f) {
    unsigned int u = __float_as_uint(f);
    unsigned int r = (u + 0x7fffu + ((u >> 16) & 1u)) >> 16;
    return (unsigned short)r;
}

static __device__ inline void gl_lds16(const unsigned short* g, unsigned short* l) {
    __builtin_amdgcn_global_load_lds(
        (const __attribute__((address_space(1))) void*)g,
        (__attribute__((address_space(3))) void*)l, 16, 0, 0);
}

// ---------------------------------------------------------------------------
// Fused prep: one launch, blockIdx-partitioned.
//   [0, 8192)        conv_x : x fp32 -> xb bf16
//   [8192, 8256)     decode_mask -> pmf f32 [B][SEQ] (1/0, CLS=1),
//                    mkl f32 [B][SEQ] (0 / -1e9), zrow f32 [SEQ] (zeros)
//   [8256, 9024)     wtrans Wqkv -> wqt bf16 [1536][512]
//   [9024, 9280)     wtrans Wout -> wot bf16 [512][512]
// ---------------------------------------------------------------------------
#define PREP_CONV   8192
#define PREP_MASK   (PREP_CONV + 64)
#define PREP_WQ     (PREP_MASK + (1536 / 32) * (EMB / 32))
#define PREP_TOTAL  (PREP_WQ + (EMB / 32) * (EMB / 32))

__global__ __launch_bounds__(256) void prep(const float* __restrict__ x,
                                            const void* __restrict__ mraw,
                                            const float* __restrict__ Wqkv,
                                            const float* __restrict__ Wout,
                                            ushort_t* __restrict__ xb,
                                            float* __restrict__ pmf,
                                            float* __restrict__ mkl,
                                            float* __restrict__ zrow,
                                            ushort_t* __restrict__ wqt,
                                            ushort_t* __restrict__ wot) {
    __shared__ float T[32][33];
    __shared__ int flag;
    const int bid = blockIdx.x;
    const int tid = threadIdx.x;

    if (bid < PREP_CONV) {
        const size_t i = ((size_t)bid * 256 + tid) * 4;
        float4 v = *(const float4*)&x[i];
        ushort4 o;
        o.x = f2bf(v.x); o.y = f2bf(v.y); o.z = f2bf(v.z); o.w = f2bf(v.w);
        *(ushort4*)&xb[i] = o;
    } else if (bid < PREP_MASK) {
        if (tid == 0) flag = 0;
        __syncthreads();
        const unsigned int* mi = (const unsigned int*)mraw;
        int local = 0;
        for (int i = tid; i < MASK_ELEMS / 4; i += 256) {
            if (mi[i] > 1u) local = 1;
        }
        if (local) flag = 1;
        __syncthreads();
        const int isbyte = flag;
        const unsigned char* mb = (const unsigned char*)mraw;
        const int* m32 = (const int*)mraw;
        const int i = (bid - PREP_CONV) * 256 + tid;
        const int b = i >> 11, n = i & (SEQ - 1);
        int v;
        if (n == 0) v = 1;
        else {
            const int src = b * (SEQ - 1) + n - 1;
            v = isbyte ? (int)mb[src] : (m32[src] != 0 ? 1 : 0);
        }
        pmf[i] = v ? 1.0f : 0.0f;
        mkl[i] = v ? 0.0f : -1e9f;
        if (i < SEQ) zrow[i] = 0.0f;
    } else {
        const float* src;
        ushort_t* dst;
        int N, idx;
        if (bid < PREP_WQ) {
            src = Wqkv; dst = wqt; N = 1536; idx = bid - PREP_MASK;
        } else {
            src = Wout; dst = wot; N = EMB; idx = bid - PREP_WQ;
        }
        const int nb = N / 32;
        const int n0 = (idx % nb) * 32;
        const int k0 = (idx / nb) * 32;
        {
            const int r = tid >> 3, c4 = (tid & 7) * 4;
            *(float4*)&T[r][c4] = *(const float4*)&src[(size_t)(k0 + r) * N + n0 + c4];
        }
        __syncthreads();
        const int n = tid >> 3, k4 = (tid & 7) * 4;
        ushort4 hv;
        hv.x = f2bf(T[k4 + 0][n]);
        hv.y = f2bf(T[k4 + 1][n]);
        hv.z = f2bf(T[k4 + 2][n]);
        hv.w = f2bf(T[k4 + 3][n]);
        *(ushort4*)&dst[(size_t)(n0 + n) * EMB + k0 + k4] = hv;
    }
}

// ---------------------------------------------------------------------------
// MFMA GEMM 1: qkv = xb @ WqkvT + bqkv.
//   q -> qb [BH][N][DH] (pre-scaled by QSCALE), k -> kb, v -> vt [BH][DH][N].
// ---------------------------------------------------------------------------
__global__ __launch_bounds__(256) void qkv_mfma(const ushort_t* __restrict__ xb,
                                                const ushort_t* __restrict__ wt,
                                                const float* __restrict__ bias,
                                                ushort_t* __restrict__ qb,
                                                ushort_t* __restrict__ kb,
                                                ushort_t* __restrict__ vt) {
    __shared__ __align__(16) ushort_t As[128 * 32];
    __shared__ __align__(16) ushort_t Bs[128 * 32];
    const int tid  = threadIdx.x;
    const int w    = tid >> 6;
    const int lane = tid & 63;
    const int l16  = lane & 15;
    const int quad = lane >> 4;
    const int wq   = w >> 1;
    const int wn   = w & 1;
    const int row0 = blockIdx.y * 128;
    const int col0 = blockIdx.x * 128;

    float4e acc[4][4];
    #pragma unroll
    for (int i = 0; i < 4; ++i)
        #pragma unroll
        for (int j = 0; j < 4; ++j) acc[i][j] = (float4e){0.f, 0.f, 0.f, 0.f};

    const int srow = tid >> 2;
    const int csrc = (tid & 3) ^ (srow & 3);

    for (int k0 = 0; k0 < EMB; k0 += 32) {
        #pragma unroll
        for (int s = 0; s < 2; ++s) {
            const int row = s * 64 + srow;
            gl_lds16(xb + (size_t)(row0 + row) * EMB + k0 + csrc * 8,
                     As + s * 2048 + w * 512);
            gl_lds16(wt + (size_t)(col0 + row) * EMB + k0 + csrc * 8,
                     Bs + s * 2048 + w * 512);
        }
        __syncthreads();
        short8 af[4], bf[4];
        #pragma unroll
        for (int mt = 0; mt < 4; ++mt) {
            const int rm = wq * 64 + mt * 16 + l16;
            af[mt] = *(const short8*)(As + rm * 32 + ((quad ^ (rm & 3)) * 8));
        }
        #pragma unroll
        for (int nt = 0; nt < 4; ++nt) {
            const int rn = wn * 64 + nt * 16 + l16;
            bf[nt] = *(const short8*)(Bs + rn * 32 + ((quad ^ (rn & 3)) * 8));
        }
        #pragma unroll
        for (int mt = 0; mt < 4; ++mt)
            #pragma unroll
            for (int nt = 0; nt < 4; ++nt)
                acc[mt][nt] = __builtin_amdgcn_mfma_f32_16x16x32_bf16(af[mt], bf[nt], acc[mt][nt], 0, 0, 0);
        __syncthreads();
    }

    #pragma unroll
    for (int nt = 0; nt < 4; ++nt) {
        const int cb    = col0 + wn * 64 + nt * 16;
        const int which = cb >> 9;
        const int h     = (cb >> 6) & 7;
        const int dcol  = (cb & 63) + l16;
        const float bz  = bias[cb + l16];
        if (which == 2) {
            #pragma unroll
            for (int mt = 0; mt < 4; ++mt) {
                const int rg = row0 + wq * 64 + mt * 16 + quad * 4;
                const int b = rg >> 11, n = rg & (SEQ - 1);
                ushort4 ov;
                ov.x = f2bf(acc[mt][nt][0] + bz);
                ov.y = f2bf(acc[mt][nt][1] + bz);
                ov.z = f2bf(acc[mt][nt][2] + bz);
                ov.w = f2bf(acc[mt][nt][3] + bz);
                *(ushort4*)&vt[((size_t)(b * NH + h) * DH + dcol) * SEQ + n] = ov;
            }
        } else {
            ushort_t* base = (which == 0) ? qb : kb;
            const float sc = (which == 0) ? QSCALE : 1.0f;
            #pragma unroll
            for (int mt = 0; mt < 4; ++mt) {
                #pragma unroll
                for (int i = 0; i < 4; ++i) {
                    const int rg = row0 + wq * 64 + mt * 16 + quad * 4 + i;
                    const int b = rg >> 11;
                    const int n = rg & (SEQ - 1);
                    base[((size_t)(b * NH + h) * SEQ + n) * DH + dcol] =
                        f2bf((acc[mt][nt][i] + bz) * sc);
                }
            }
        }
    }
}

// ---------------------------------------------------------------------------
// MFMA flash attention v12: in-block split-K (chains/CU 16 -> 32).
//   Diagnosis: R0/R1/R4 all ~110-116us across occupancy/VALU/LDS changes;
//   every pipe <40%. Latency-bound with chains/CU capped at 16 by the q-only
//   decomposition. Fixed-max softmax (p=exp2(st), no running max) makes
//   split-K partials ADDITIVE: O = O0+O1, l = l0+l1 -> trivial combine.
//   Structure: 4-wave blocks; waves{0,1}=keys[0,1024), waves{2,3}=[1024,2048),
//   each wave 64q (2 chains) of the same 128-q tile. KVBLK=32, per-half K/V
//   dbuf (4KB tiles) -> LDS 33KB, 4 blocks/CU, 16 waves/CU, 32 chains/CU.
//   Combine in-LDS: half-1 writes partial O(f32)+l into dead K/V smem after
//   the loop; half-0 adds, divides, writes ab. No extra HBM traffic.
//   Per-chain math identical to proven R4 (one 32-key s-phase per kt; V tile
//   re-laid [32 rows][2x32 keys] = 128B rows so the XOR swizzle keeps the
//   proven conflict profile). C-init mask fold + permlane32_swap as R4.
// ---------------------------------------------------------------------------
__device__ inline void stage_half(const ushort_t* kbh, const ushort_t* vbh,
                                  int keybase, ushort_t* Kd, ushort_t* Vd,
                                  int wp, int lane) {
    #pragma unroll
    for (int j = 0; j < 2; ++j) {
        const int c = j * 128 + wp * 64 + lane;
        const int r = c >> 3;                  // 0..31
        const int q = (c & 7) ^ (r & 7);       // pre-swizzled slot
        // K tile [32 keys][64 dh]: slot q = dh group
        gl_lds16(kbh + (size_t)(keybase + r) * DH + q * 8,
                 Kd + (size_t)(j * 128 + wp * 64) * 8);
        // V tile [32 rows][8 slots]: slot q -> d = q>>2 (dh half), kg = q&3
        gl_lds16(vbh + (size_t)((q >> 2) * 32 + r) * SEQ + keybase + (q & 3) * 8,
                 Vd + (size_t)(j * 128 + wp * 64) * 8);
    }
}

__global__ __launch_bounds__(256, 4) void attn_mfma(const ushort_t* __restrict__ qb,
                                                    const ushort_t* __restrict__ kb,
                                                    const ushort_t* __restrict__ vt,
                                                    const float* __restrict__ pmf,
                                                    const float* __restrict__ mkl,
                                                    ushort_t* __restrict__ ab) {
    // 32KB: K/V tiles during loop; partial-O exchange in epilogue.
    // tile(half,buf,kv) = smem + ((half*2+buf)*2+kv)*2048  (2048 ushorts = 4KB)
    __shared__ __align__(16) ushort_t smem[16384];
    __shared__ float Lx[2][2][64];   // [half][wp][q]

    const int tid  = threadIdx.x;
    const int w    = tid >> 6;         // 0..3
    const int half = w >> 1;           // key half
    const int wp   = w & 1;            // q sub-tile within block
    const int lane = tid & 63;
    const int l5   = lane & 31;
    const int h    = lane >> 5;        // half-wave
    // XCD swizzle: xcd = bid&7 gets bh in [xcd*8, xcd*8+8) -> K+V L2-resident.
    const int bid = blockIdx.x;        // 0..1023
    const int ord = bid >> 3;          // 0..127
    const int bh  = (bid & 7) * 8 + (ord >> 4);
    const int qt  = ord & 15;
    const int b   = bh >> 3;
    const int hh  = bh & 7;
    const int q0  = qt * 128 + wp * 64;   // wave's first q row

    // Q fragments (B-operand of S^T): n=q=l5, k=dh=kc*16+h*8+j
    const ushort_t* qbh = qb + (size_t)bh * SEQ * DH;
    short8 qf[2][4];
    #pragma unroll
    for (int t = 0; t < 2; ++t)
        #pragma unroll
        for (int kc = 0; kc < 4; ++kc)
            qf[t][kc] = *(const short8*)(qbh + (size_t)(q0 + t * 32 + l5) * DH + kc * 16 + h * 8);

    // q mask: masked-q chains get zeroed Q and st-init 0 -> p=1 for every key
    // in BOTH halves -> l = 2048, O/l = mean(V): reference semantics.
    bool qv[2];
    #pragma unroll
    for (int t = 0; t < 2; ++t) {
        const float mq = pmf[b * SEQ + q0 + t * 32 + l5];
        qv[t] = (mq != 0.0f);
        if (!qv[t]) {
            const short8 z8 = {0, 0, 0, 0, 0, 0, 0, 0};
            #pragma unroll
            for (int kc = 0; kc < 4; ++kc) qf[t][kc] = z8;
        }
    }

    const ushort_t* kbh = kb + (size_t)bh * SEQ * DH;
    const ushort_t* vbh = vt + (size_t)bh * DH * SEQ;
    const float*    mrow = mkl + b * SEQ + half * 1024;

    float16e o[2][2];   // [t][dh-tile]
    #pragma unroll
    for (int t = 0; t < 2; ++t)
        #pragma unroll
        for (int d = 0; d < 2; ++d) o[t][d] = (float16e)0.0f;
    float l_i[2] = {0.f, 0.f};

    ushort_t* const Kbuf[2] = {smem + (half * 2 + 0) * 2 * 2048,
                               smem + (half * 2 + 1) * 2 * 2048};
    ushort_t* const Vbuf[2] = {Kbuf[0] + 2048, Kbuf[1] + 2048};

    stage_half(kbh, vbh, half * 1024, Kbuf[0], Vbuf[0], wp, lane);

    for (int kt = 0; kt < 32; ++kt) {
        __syncthreads();   // staged tiles visible; drain covered by prev compute
        const int cur = kt & 1;
        if (kt < 31)
            stage_half(kbh, vbh, half * 1024 + (kt + 1) * 32,
                       Kbuf[cur ^ 1], Vbuf[cur ^ 1], wp, lane);

        // ---- mask logits (broadcast, L1-hot): reg r -> key (r&3)+8*(r>>2)+4h
        float4e m4[4];
        #pragma unroll
        for (int g2 = 0; g2 < 4; ++g2)
            m4[g2] = *(const float4e*)(mrow + kt * 32 + g2 * 8 + h * 4);

        // ---- C-init: st = qvalid ? mask-logit : 0  (cndmask) ----
        float16e st[2];
        #pragma unroll
        for (int g2 = 0; g2 < 4; ++g2)
            #pragma unroll
            for (int j = 0; j < 4; ++j) {
                const float v = m4[g2][j];
                st[0][g2 * 4 + j] = qv[0] ? v : 0.0f;
                st[1][g2 * 4 + j] = qv[1] ? v : 0.0f;
            }

        // ---- S^T = K·Q for this 32-key tile (A=K from LDS, B=Q regs) ----
        short8 kf[4];
        #pragma unroll
        for (int kc = 0; kc < 4; ++kc)
            kf[kc] = *(const short8*)(Kbuf[cur] + l5 * 64 + (((kc * 2 + h) ^ (l5 & 7)) * 8));
        __builtin_amdgcn_s_setprio(1);
        #pragma unroll
        for (int kc = 0; kc < 4; ++kc) {
            st[0] = __builtin_amdgcn_mfma_f32_32x32x16_bf16(kf[kc], qf[0][kc], st[0], 0, 0, 0);
            st[1] = __builtin_amdgcn_mfma_f32_32x32x16_bf16(kf[kc], qf[1][kc], st[1], 0, 0, 0);
        }
        __builtin_amdgcn_s_setprio(0);

        // ---- softmax p = exp2(st); pack bf16 pairs; permlane32_swap ----
        short8 af[2][2];
        #pragma unroll
        for (int t = 0; t < 2; ++t) {
            unsigned int a[8];
            float lacc = 0.f;
            #pragma unroll
            for (int j = 0; j < 8; ++j) {
                const float p0 = __builtin_amdgcn_exp2f(st[t][2 * j]);
                const float p1 = __builtin_amdgcn_exp2f(st[t][2 * j + 1]);
                lacc += p0 + p1;
                a[j] = (__float_as_uint(p0) >> 16) | (__float_as_uint(p1) & 0xffff0000u);
            }
            l_i[t] += lacc;
            #pragma unroll
            for (int c = 0; c < 2; ++c) {
                const uint2e r02 = __builtin_amdgcn_permlane32_swap(a[4 * c],     a[4 * c + 2], false, false);
                const uint2e r13 = __builtin_amdgcn_permlane32_swap(a[4 * c + 1], a[4 * c + 3], false, false);
                uint4e fv;
                fv.x = r02[0];
                fv.y = r13[0];
                fv.z = r02[1];
                fv.w = r13[1];
                af[t][c] = __builtin_bit_cast(short8, fv);
            }
        }

        // ---- PV: O[t][d] += P @ V (A=P regs, B=V from LDS) ----
        // V tile [32 rows][128B]: row = l5, slot = (d*4 + c*2 + h) ^ (l5&7)
        __builtin_amdgcn_s_setprio(1);
        #pragma unroll
        for (int c = 0; c < 2; ++c) {
            #pragma unroll
            for (int d = 0; d < 2; ++d) {
                const short8 vf = *(const short8*)(Vbuf[cur] + l5 * 64 +
                                   (((d * 4 + c * 2 + h) ^ (l5 & 7)) * 8));
                o[0][d] = __builtin_amdgcn_mfma_f32_32x32x16_bf16(af[0][c], vf, o[0][d], 0, 0, 0);
                o[1][d] = __builtin_amdgcn_mfma_f32_32x32x16_bf16(af[1][c], vf, o[1][d], 0, 0, 0);
            }
        }
        __builtin_amdgcn_s_setprio(0);
    }

    // ---- combine: l across half-waves, then across key-halves via LDS ----
    float lt[2];
    #pragma unroll
    for (int t = 0; t < 2; ++t)
        lt[t] = l_i[t] + __shfl_xor(l_i[t], 32);

    __syncthreads();                   // all K/V LDS reads complete
    float* Ox = (float*)smem;          // [wp][64 q][64 dh] f32 = 32KB
    if (half == 1) {
        #pragma unroll
        for (int t = 0; t < 2; ++t) {
            Lx[1][wp][t * 32 + l5] = lt[t];
            #pragma unroll
            for (int r = 0; r < 16; ++r) {
                const int ql = (r & 3) + 8 * (r >> 2) + 4 * h;
                #pragma unroll
                for (int d = 0; d < 2; ++d)
                    Ox[(size_t)(wp * 64 + t * 32 + ql) * 64 + d * 32 + l5] = o[t][d][r];
            }
        }
    } else {
        #pragma unroll
        for (int t = 0; t < 2; ++t)
            Lx[0][wp][t * 32 + l5] = lt[t];
    }
    __syncthreads();
    if (half == 0) {
        ushort_t* ob = ab + ((size_t)b * SEQ + q0) * EMB + hh * DH;
        #pragma unroll
        for (int t = 0; t < 2; ++t) {
            #pragma unroll
            for (int r = 0; r < 16; ++r) {
                const int ql = (r & 3) + 8 * (r >> 2) + 4 * h;
                const float inv = 1.0f / (Lx[0][wp][t * 32 + ql] + Lx[1][wp][t * 32 + ql]);
                #pragma unroll
                for (int d = 0; d < 2; ++d) {
                    const float val = o[t][d][r] +
                        Ox[(size_t)(wp * 64 + t * 32 + ql) * 64 + d * 32 + l5];
                    ob[(size_t)(t * 32 + ql) * EMB + d * 32 + l5] = f2bf(val * inv);
                }
            }
        }
    }
}

// ---------------------------------------------------------------------------
// MFMA GEMM 2: out = ab @ WoutT + bout (fp32 out).
// ---------------------------------------------------------------------------
__global__ __launch_bounds__(256) void out_mfma(const ushort_t* __restrict__ ab,
                                                const ushort_t* __restrict__ wot,
                                                const float* __restrict__ bias,
                                                float* __restrict__ out) {
    __shared__ __align__(16) ushort_t As[128 * 32];
    __shared__ __align__(16) ushort_t Bs[128 * 32];
    const int tid  = threadIdx.x;
    const int w    = tid >> 6;
    const int lane = tid & 63;
    const int l16  = lane & 15;
    const int quad = lane >> 4;
    const int wq   = w >> 1;
    const int wn   = w & 1;
    const int row0 = blockIdx.y * 128;
    const int col0 = blockIdx.x * 128;

    float4e acc[4][4];
    #pragma unroll
    for (int i = 0; i < 4; ++i)
        #pragma unroll
        for (int j = 0; j < 4; ++j) acc[i][j] = (float4e){0.f, 0.f, 0.f, 0.f};

    const int srow = tid >> 2;
    const int csrc = (tid & 3) ^ (srow & 3);

    for (int k0 = 0; k0 < EMB; k0 += 32) {
        #pragma unroll
        for (int s = 0; s < 2; ++s) {
            const int row = s * 64 + srow;
            gl_lds16(ab + (size_t)(row0 + row) * EMB + k0 + csrc * 8,
                     As + s * 2048 + w * 512);
            gl_lds16(wot + (size_t)(col0 + row) * EMB + k0 + csrc * 8,
                     Bs + s * 2048 + w * 512);
        }
        __syncthreads();
        short8 af[4], bf[4];
        #pragma unroll
        for (int mt = 0; mt < 4; ++mt) {
            const int rm = wq * 64 + mt * 16 + l16;
            af[mt] = *(const short8*)(As + rm * 32 + ((quad ^ (rm & 3)) * 8));
        }
        #pragma unroll
        for (int nt = 0; nt < 4; ++nt) {
            const int rn = wn * 64 + nt * 16 + l16;
            bf[nt] = *(const short8*)(Bs + rn * 32 + ((quad ^ (rn & 3)) * 8));
        }
        #pragma unroll
        for (int mt = 0; mt < 4; ++mt)
            #pragma unroll
            for (int nt = 0; nt < 4; ++nt)
                acc[mt][nt] = __builtin_amdgcn_mfma_f32_16x16x32_bf16(af[mt], bf[nt], acc[mt][nt], 0, 0, 0);
        __syncthreads();
    }

    #pragma unroll
    for (int nt = 0; nt < 4; ++nt) {
        const int col_g = col0 + wn * 64 + nt * 16 + l16;
        const float bz = bias[col_g];
        #pragma unroll
        for (int mt = 0; mt < 4; ++mt) {
            #pragma unroll
            for (int i = 0; i < 4; ++i) {
                const int row_g = row0 + wq * 64 + mt * 16 + quad * 4 + i;
                out[(size_t)row_g * EMB + col_g] = acc[mt][nt][i] + bz;
            }
        }
    }
}

// ---------------------------------------------------------------------------
extern "C" void kernel_launch(void* const* d_in, const int* in_sizes, int n_in,
                              void* d_out, int out_size, void* d_ws, size_t ws_size,
                              hipStream_t stream) {
    const float* x    = (const float*)d_in[0];
    const void*  mask = d_in[1];
    const float* Wqkv = (const float*)d_in[2];
    const float* bqkv = (const float*)d_in[3];
    const float* Wout = (const float*)d_in[4];
    const float* bout = (const float*)d_in[5];
    float* out = (float*)d_out;

    ushort_t* xb  = (ushort_t*)d_ws;                 // [16384][512]
    ushort_t* wqt = xb + (size_t)MROWS * EMB;        // [1536][512]
    ushort_t* wot = wqt + (size_t)1536 * EMB;        // [512][512]
    ushort_t* qb  = wot + (size_t)EMB * EMB;         // [BH][N][DH]
    ushort_t* kb  = qb + QKV_ELEMS;
    ushort_t* vt  = kb + QKV_ELEMS;                  // [BH][DH][N]
    ushort_t* ab  = vt + QKV_ELEMS;                  // [B][N][EMB]
    float*    pmf = (float*)(ab + (size_t)MROWS * EMB); // f32 [B][SEQ]
    float*    mkl = pmf + (size_t)BB * SEQ;             // f32 [B][SEQ]
    float*    zrw = mkl + (size_t)BB * SEQ;             // f32 [SEQ]

    prep<<<dim3(PREP_TOTAL), 256, 0, stream>>>(x, mask, Wqkv, Wout, xb, pmf, mkl, zrw, wqt, wot);
    qkv_mfma<<<dim3(1536 / 128, MROWS / 128), 256, 0, stream>>>(xb, wqt, bqkv, qb, kb, vt);
    attn_mfma<<<dim3(NBH * (SEQ / 128)), 256, 0, stream>>>(qb, kb, vt, pmf, mkl, ab);
    out_mfma<<<dim3(EMB / 128, MROWS / 128), 256, 0, stream>>>(ab, wot, bout, out);
}

// Round 7
// 272.521 us; speedup vs baseline: 2.4842x; 2.4842x over previous
//
#include <hip/hip_runtime.h>
#include <math.h>

#define BB  8
#define SEQ 2048
#define EMB 512
#define NH  8
#define DH  64
#define NBH (BB * NH)                      // 64
#define MROWS (BB * SEQ)                   // 16384
#define QKV_ELEMS ((size_t)NBH * SEQ * DH) // 8388608
#define MASK_ELEMS (BB * (SEQ - 1))        // 16376
// 512^-0.5 * log2(e): q pre-scaled so softmax uses exp2 directly
#define QSCALE 0.06375871307545f

typedef __attribute__((ext_vector_type(8)))  short short8;
typedef __attribute__((ext_vector_type(4)))  float float4e;
typedef __attribute__((ext_vector_type(16))) float float16e;
typedef __attribute__((ext_vector_type(4)))  unsigned int uint4e;
typedef __attribute__((ext_vector_type(2)))  unsigned int uint2e;
typedef unsigned short ushort_t;

static __device__ inline unsigned short f2bf(float f) {
    unsigned int u = __float_as_uint(f);
    unsigned int r = (u + 0x7fffu + ((u >> 16) & 1u)) >> 16;
    return (unsigned short)r;
}

static __device__ inline void gl_lds16(const unsigned short* g, unsigned short* l) {
    __builtin_amdgcn_global_load_lds(
        (const __attribute__((address_space(1))) void*)g,
        (__attribute__((address_space(3))) void*)l, 16, 0, 0);
}

// ---------------------------------------------------------------------------
// Fused prep: one launch, blockIdx-partitioned.
//   [0, 8192)        conv_x : x fp32 -> xb bf16
//   [8192, 8256)     decode_mask -> pmf f32 [B][SEQ] (1/0, CLS=1),
//                    mkl f32 [B][SEQ] (0 / -1e9), zrow f32 [SEQ] (zeros)
//   [8256, 9024)     wtrans Wqkv -> wqt bf16 [1536][512]
//   [9024, 9280)     wtrans Wout -> wot bf16 [512][512]
// ---------------------------------------------------------------------------
#define PREP_CONV   8192
#define PREP_MASK   (PREP_CONV + 64)
#define PREP_WQ     (PREP_MASK + (1536 / 32) * (EMB / 32))
#define PREP_TOTAL  (PREP_WQ + (EMB / 32) * (EMB / 32))

__global__ __launch_bounds__(256) void prep(const float* __restrict__ x,
                                            const void* __restrict__ mraw,
                                            const float* __restrict__ Wqkv,
                                            const float* __restrict__ Wout,
                                            ushort_t* __restrict__ xb,
                                            float* __restrict__ pmf,
                                            float* __restrict__ mkl,
                                            float* __restrict__ zrow,
                                            ushort_t* __restrict__ wqt,
                                            ushort_t* __restrict__ wot) {
    __shared__ float T[32][33];
    __shared__ int flag;
    const int bid = blockIdx.x;
    const int tid = threadIdx.x;

    if (bid < PREP_CONV) {
        const size_t i = ((size_t)bid * 256 + tid) * 4;
        float4 v = *(const float4*)&x[i];
        ushort4 o;
        o.x = f2bf(v.x); o.y = f2bf(v.y); o.z = f2bf(v.z); o.w = f2bf(v.w);
        *(ushort4*)&xb[i] = o;
    } else if (bid < PREP_MASK) {
        if (tid == 0) flag = 0;
        __syncthreads();
        const unsigned int* mi = (const unsigned int*)mraw;
        int local = 0;
        for (int i = tid; i < MASK_ELEMS / 4; i += 256) {
            if (mi[i] > 1u) local = 1;
        }
        if (local) flag = 1;
        __syncthreads();
        const int isbyte = flag;
        const unsigned char* mb = (const unsigned char*)mraw;
        const int* m32 = (const int*)mraw;
        const int i = (bid - PREP_CONV) * 256 + tid;
        const int b = i >> 11, n = i & (SEQ - 1);
        int v;
        if (n == 0) v = 1;
        else {
            const int src = b * (SEQ - 1) + n - 1;
            v = isbyte ? (int)mb[src] : (m32[src] != 0 ? 1 : 0);
        }
        pmf[i] = v ? 1.0f : 0.0f;
        mkl[i] = v ? 0.0f : -1e9f;
        if (i < SEQ) zrow[i] = 0.0f;
    } else {
        const float* src;
        ushort_t* dst;
        int N, idx;
        if (bid < PREP_WQ) {
            src = Wqkv; dst = wqt; N = 1536; idx = bid - PREP_MASK;
        } else {
            src = Wout; dst = wot; N = EMB; idx = bid - PREP_WQ;
        }
        const int nb = N / 32;
        const int n0 = (idx % nb) * 32;
        const int k0 = (idx / nb) * 32;
        {
            const int r = tid >> 3, c4 = (tid & 7) * 4;
            *(float4*)&T[r][c4] = *(const float4*)&src[(size_t)(k0 + r) * N + n0 + c4];
        }
        __syncthreads();
        const int n = tid >> 3, k4 = (tid & 7) * 4;
        ushort4 hv;
        hv.x = f2bf(T[k4 + 0][n]);
        hv.y = f2bf(T[k4 + 1][n]);
        hv.z = f2bf(T[k4 + 2][n]);
        hv.w = f2bf(T[k4 + 3][n]);
        *(ushort4*)&dst[(size_t)(n0 + n) * EMB + k0 + k4] = hv;
    }
}

// ---------------------------------------------------------------------------
// MFMA GEMM 1: qkv = xb @ WqkvT + bqkv.
//   q -> qb [BH][N][DH] (pre-scaled by QSCALE), k -> kb, v -> vt [BH][DH][N].
// ---------------------------------------------------------------------------
__global__ __launch_bounds__(256) void qkv_mfma(const ushort_t* __restrict__ xb,
                                                const ushort_t* __restrict__ wt,
                                                const float* __restrict__ bias,
                                                ushort_t* __restrict__ qb,
                                                ushort_t* __restrict__ kb,
                                                ushort_t* __restrict__ vt) {
    __shared__ __align__(16) ushort_t As[128 * 32];
    __shared__ __align__(16) ushort_t Bs[128 * 32];
    const int tid  = threadIdx.x;
    const int w    = tid >> 6;
    const int lane = tid & 63;
    const int l16  = lane & 15;
    const int quad = lane >> 4;
    const int wq   = w >> 1;
    const int wn   = w & 1;
    const int row0 = blockIdx.y * 128;
    const int col0 = blockIdx.x * 128;

    float4e acc[4][4];
    #pragma unroll
    for (int i = 0; i < 4; ++i)
        #pragma unroll
        for (int j = 0; j < 4; ++j) acc[i][j] = (float4e){0.f, 0.f, 0.f, 0.f};

    const int srow = tid >> 2;
    const int csrc = (tid & 3) ^ (srow & 3);

    for (int k0 = 0; k0 < EMB; k0 += 32) {
        #pragma unroll
        for (int s = 0; s < 2; ++s) {
            const int row = s * 64 + srow;
            gl_lds16(xb + (size_t)(row0 + row) * EMB + k0 + csrc * 8,
                     As + s * 2048 + w * 512);
            gl_lds16(wt + (size_t)(col0 + row) * EMB + k0 + csrc * 8,
                     Bs + s * 2048 + w * 512);
        }
        __syncthreads();
        short8 af[4], bf[4];
        #pragma unroll
        for (int mt = 0; mt < 4; ++mt) {
            const int rm = wq * 64 + mt * 16 + l16;
            af[mt] = *(const short8*)(As + rm * 32 + ((quad ^ (rm & 3)) * 8));
        }
        #pragma unroll
        for (int nt = 0; nt < 4; ++nt) {
            const int rn = wn * 64 + nt * 16 + l16;
            bf[nt] = *(const short8*)(Bs + rn * 32 + ((quad ^ (rn & 3)) * 8));
        }
        #pragma unroll
        for (int mt = 0; mt < 4; ++mt)
            #pragma unroll
            for (int nt = 0; nt < 4; ++nt)
                acc[mt][nt] = __builtin_amdgcn_mfma_f32_16x16x32_bf16(af[mt], bf[nt], acc[mt][nt], 0, 0, 0);
        __syncthreads();
    }

    #pragma unroll
    for (int nt = 0; nt < 4; ++nt) {
        const int cb    = col0 + wn * 64 + nt * 16;
        const int which = cb >> 9;
        const int h     = (cb >> 6) & 7;
        const int dcol  = (cb & 63) + l16;
        const float bz  = bias[cb + l16];
        if (which == 2) {
            #pragma unroll
            for (int mt = 0; mt < 4; ++mt) {
                const int rg = row0 + wq * 64 + mt * 16 + quad * 4;
                const int b = rg >> 11, n = rg & (SEQ - 1);
                ushort4 ov;
                ov.x = f2bf(acc[mt][nt][0] + bz);
                ov.y = f2bf(acc[mt][nt][1] + bz);
                ov.z = f2bf(acc[mt][nt][2] + bz);
                ov.w = f2bf(acc[mt][nt][3] + bz);
                *(ushort4*)&vt[((size_t)(b * NH + h) * DH + dcol) * SEQ + n] = ov;
            }
        } else {
            ushort_t* base = (which == 0) ? qb : kb;
            const float sc = (which == 0) ? QSCALE : 1.0f;
            #pragma unroll
            for (int mt = 0; mt < 4; ++mt) {
                #pragma unroll
                for (int i = 0; i < 4; ++i) {
                    const int rg = row0 + wq * 64 + mt * 16 + quad * 4 + i;
                    const int b = rg >> 11;
                    const int n = rg & (SEQ - 1);
                    base[((size_t)(b * NH + h) * SEQ + n) * DH + dcol] =
                        f2bf((acc[mt][nt][i] + bz) * sc);
                }
            }
        }
    }
}

// ---------------------------------------------------------------------------
// MFMA flash attention v13: R6 split-K structure + FIXED launch bounds.
//   R6 failed on a toolchain rule discovered by cross-round evidence:
//   __launch_bounds__(T, W) caps VGPR at 256/W on this hipcc — (256,4)->64
//   forced the ~120-VGPR kernel into catastrophic scratch spill (2.25 GB of
//   FETCH+WRITE was spill traffic, not K/V). Fix: (256,2) -> cap 128.
//   Occupancy then comes from LDS (33.8KB -> 4 blocks/CU): 16 waves/CU,
//   32 chains/CU (split-K doubling vs the R0-R5 16-chain plateau).
//   All math identical to R6 (verified correct: passed, absmax unchanged).
// ---------------------------------------------------------------------------
__device__ inline void stage_half(const ushort_t* kbh, const ushort_t* vbh,
                                  int keybase, ushort_t* Kd, ushort_t* Vd,
                                  int wp, int lane) {
    #pragma unroll
    for (int j = 0; j < 2; ++j) {
        const int c = j * 128 + wp * 64 + lane;
        const int r = c >> 3;                  // 0..31
        const int q = (c & 7) ^ (r & 7);       // pre-swizzled slot
        // K tile [32 keys][64 dh]: slot q = dh group
        gl_lds16(kbh + (size_t)(keybase + r) * DH + q * 8,
                 Kd + (size_t)(j * 128 + wp * 64) * 8);
        // V tile [32 rows][8 slots]: slot q -> d = q>>2 (dh half), kg = q&3
        gl_lds16(vbh + (size_t)((q >> 2) * 32 + r) * SEQ + keybase + (q & 3) * 8,
                 Vd + (size_t)(j * 128 + wp * 64) * 8);
    }
}

__global__ __launch_bounds__(256, 2) void attn_mfma(const ushort_t* __restrict__ qb,
                                                    const ushort_t* __restrict__ kb,
                                                    const ushort_t* __restrict__ vt,
                                                    const float* __restrict__ pmf,
                                                    const float* __restrict__ mkl,
                                                    ushort_t* __restrict__ ab) {
    // 32KB: K/V tiles during loop; partial-O exchange in epilogue.
    // tile(half,buf,kv) = smem + ((half*2+buf)*2+kv)*2048  (2048 ushorts = 4KB)
    __shared__ __align__(16) ushort_t smem[16384];
    __shared__ float Lx[2][2][64];   // [half][wp][q]

    const int tid  = threadIdx.x;
    const int w    = tid >> 6;         // 0..3
    const int half = w >> 1;           // key half
    const int wp   = w & 1;            // q sub-tile within block
    const int lane = tid & 63;
    const int l5   = lane & 31;
    const int h    = lane >> 5;        // half-wave
    // XCD swizzle: xcd = bid&7 gets bh in [xcd*8, xcd*8+8) -> K+V L2-resident.
    const int bid = blockIdx.x;        // 0..1023
    const int ord = bid >> 3;          // 0..127
    const int bh  = (bid & 7) * 8 + (ord >> 4);
    const int qt  = ord & 15;
    const int b   = bh >> 3;
    const int hh  = bh & 7;
    const int q0  = qt * 128 + wp * 64;   // wave's first q row

    // Q fragments (B-operand of S^T): n=q=l5, k=dh=kc*16+h*8+j
    const ushort_t* qbh = qb + (size_t)bh * SEQ * DH;
    short8 qf[2][4];
    #pragma unroll
    for (int t = 0; t < 2; ++t)
        #pragma unroll
        for (int kc = 0; kc < 4; ++kc)
            qf[t][kc] = *(const short8*)(qbh + (size_t)(q0 + t * 32 + l5) * DH + kc * 16 + h * 8);

    // q mask: masked-q chains get zeroed Q and st-init 0 -> p=1 for every key
    // in BOTH halves -> l = 2048, O/l = mean(V): reference semantics.
    bool qv[2];
    #pragma unroll
    for (int t = 0; t < 2; ++t) {
        const float mq = pmf[b * SEQ + q0 + t * 32 + l5];
        qv[t] = (mq != 0.0f);
        if (!qv[t]) {
            const short8 z8 = {0, 0, 0, 0, 0, 0, 0, 0};
            #pragma unroll
            for (int kc = 0; kc < 4; ++kc) qf[t][kc] = z8;
        }
    }

    const ushort_t* kbh = kb + (size_t)bh * SEQ * DH;
    const ushort_t* vbh = vt + (size_t)bh * DH * SEQ;
    const float*    mrow = mkl + b * SEQ + half * 1024;

    float16e o[2][2];   // [t][dh-tile]
    #pragma unroll
    for (int t = 0; t < 2; ++t)
        #pragma unroll
        for (int d = 0; d < 2; ++d) o[t][d] = (float16e)0.0f;
    float l_i[2] = {0.f, 0.f};

    ushort_t* const Kbuf[2] = {smem + (half * 2 + 0) * 2 * 2048,
                               smem + (half * 2 + 1) * 2 * 2048};
    ushort_t* const Vbuf[2] = {Kbuf[0] + 2048, Kbuf[1] + 2048};

    stage_half(kbh, vbh, half * 1024, Kbuf[0], Vbuf[0], wp, lane);

    for (int kt = 0; kt < 32; ++kt) {
        __syncthreads();   // staged tiles visible; drain covered by prev compute
        const int cur = kt & 1;
        if (kt < 31)
            stage_half(kbh, vbh, half * 1024 + (kt + 1) * 32,
                       Kbuf[cur ^ 1], Vbuf[cur ^ 1], wp, lane);

        // ---- mask logits (broadcast, L1-hot): reg r -> key (r&3)+8*(r>>2)+4h
        float4e m4[4];
        #pragma unroll
        for (int g2 = 0; g2 < 4; ++g2)
            m4[g2] = *(const float4e*)(mrow + kt * 32 + g2 * 8 + h * 4);

        // ---- C-init: st = qvalid ? mask-logit : 0  (cndmask) ----
        float16e st[2];
        #pragma unroll
        for (int g2 = 0; g2 < 4; ++g2)
            #pragma unroll
            for (int j = 0; j < 4; ++j) {
                const float v = m4[g2][j];
                st[0][g2 * 4 + j] = qv[0] ? v : 0.0f;
                st[1][g2 * 4 + j] = qv[1] ? v : 0.0f;
            }

        // ---- S^T = K·Q for this 32-key tile (A=K from LDS, B=Q regs) ----
        short8 kf[4];
        #pragma unroll
        for (int kc = 0; kc < 4; ++kc)
            kf[kc] = *(const short8*)(Kbuf[cur] + l5 * 64 + (((kc * 2 + h) ^ (l5 & 7)) * 8));
        __builtin_amdgcn_s_setprio(1);
        #pragma unroll
        for (int kc = 0; kc < 4; ++kc) {
            st[0] = __builtin_amdgcn_mfma_f32_32x32x16_bf16(kf[kc], qf[0][kc], st[0], 0, 0, 0);
            st[1] = __builtin_amdgcn_mfma_f32_32x32x16_bf16(kf[kc], qf[1][kc], st[1], 0, 0, 0);
        }
        __builtin_amdgcn_s_setprio(0);

        // ---- softmax p = exp2(st); pack bf16 pairs; permlane32_swap ----
        short8 af[2][2];
        #pragma unroll
        for (int t = 0; t < 2; ++t) {
            unsigned int a[8];
            float lacc = 0.f;
            #pragma unroll
            for (int j = 0; j < 8; ++j) {
                const float p0 = __builtin_amdgcn_exp2f(st[t][2 * j]);
                const float p1 = __builtin_amdgcn_exp2f(st[t][2 * j + 1]);
                lacc += p0 + p1;
                a[j] = (__float_as_uint(p0) >> 16) | (__float_as_uint(p1) & 0xffff0000u);
            }
            l_i[t] += lacc;
            #pragma unroll
            for (int c = 0; c < 2; ++c) {
                const uint2e r02 = __builtin_amdgcn_permlane32_swap(a[4 * c],     a[4 * c + 2], false, false);
                const uint2e r13 = __builtin_amdgcn_permlane32_swap(a[4 * c + 1], a[4 * c + 3], false, false);
                uint4e fv;
                fv.x = r02[0];
                fv.y = r13[0];
                fv.z = r02[1];
                fv.w = r13[1];
                af[t][c] = __builtin_bit_cast(short8, fv);
            }
        }

        // ---- PV: O[t][d] += P @ V (A=P regs, B=V from LDS) ----
        // V tile [32 rows][128B]: row = l5, slot = (d*4 + c*2 + h) ^ (l5&7)
        __builtin_amdgcn_s_setprio(1);
        #pragma unroll
        for (int c = 0; c < 2; ++c) {
            #pragma unroll
            for (int d = 0; d < 2; ++d) {
                const short8 vf = *(const short8*)(Vbuf[cur] + l5 * 64 +
                                   (((d * 4 + c * 2 + h) ^ (l5 & 7)) * 8));
                o[0][d] = __builtin_amdgcn_mfma_f32_32x32x16_bf16(af[0][c], vf, o[0][d], 0, 0, 0);
                o[1][d] = __builtin_amdgcn_mfma_f32_32x32x16_bf16(af[1][c], vf, o[1][d], 0, 0, 0);
            }
        }
        __builtin_amdgcn_s_setprio(0);
    }

    // ---- combine: l across half-waves, then across key-halves via LDS ----
    float lt[2];
    #pragma unroll
    for (int t = 0; t < 2; ++t)
        lt[t] = l_i[t] + __shfl_xor(l_i[t], 32);

    __syncthreads();                   // all K/V LDS reads complete
    float* Ox = (float*)smem;          // [wp][64 q][64 dh] f32 = 32KB
    if (half == 1) {
        #pragma unroll
        for (int t = 0; t < 2; ++t) {
            Lx[1][wp][t * 32 + l5] = lt[t];
            #pragma unroll
            for (int r = 0; r < 16; ++r) {
                const int ql = (r & 3) + 8 * (r >> 2) + 4 * h;
                #pragma unroll
                for (int d = 0; d < 2; ++d)
                    Ox[(size_t)(wp * 64 + t * 32 + ql) * 64 + d * 32 + l5] = o[t][d][r];
            }
        }
    } else {
        #pragma unroll
        for (int t = 0; t < 2; ++t)
            Lx[0][wp][t * 32 + l5] = lt[t];
    }
    __syncthreads();
    if (half == 0) {
        ushort_t* ob = ab + ((size_t)b * SEQ + q0) * EMB + hh * DH;
        #pragma unroll
        for (int t = 0; t < 2; ++t) {
            #pragma unroll
            for (int r = 0; r < 16; ++r) {
                const int ql = (r & 3) + 8 * (r >> 2) + 4 * h;
                const float inv = 1.0f / (Lx[0][wp][t * 32 + ql] + Lx[1][wp][t * 32 + ql]);
                #pragma unroll
                for (int d = 0; d < 2; ++d) {
                    const float val = o[t][d][r] +
                        Ox[(size_t)(wp * 64 + t * 32 + ql) * 64 + d * 32 + l5];
                    ob[(size_t)(t * 32 + ql) * EMB + d * 32 + l5] = f2bf(val * inv);
                }
            }
        }
    }
}

// ---------------------------------------------------------------------------
// MFMA GEMM 2: out = ab @ WoutT + bout (fp32 out).
// ---------------------------------------------------------------------------
__global__ __launch_bounds__(256) void out_mfma(const ushort_t* __restrict__ ab,
                                                const ushort_t* __restrict__ wot,
                                                const float* __restrict__ bias,
                                                float* __restrict__ out) {
    __shared__ __align__(16) ushort_t As[128 * 32];
    __shared__ __align__(16) ushort_t Bs[128 * 32];
    const int tid  = threadIdx.x;
    const int w    = tid >> 6;
    const int lane = tid & 63;
    const int l16  = lane & 15;
    const int quad = lane >> 4;
    const int wq   = w >> 1;
    const int wn   = w & 1;
    const int row0 = blockIdx.y * 128;
    const int col0 = blockIdx.x * 128;

    float4e acc[4][4];
    #pragma unroll
    for (int i = 0; i < 4; ++i)
        #pragma unroll
        for (int j = 0; j < 4; ++j) acc[i][j] = (float4e){0.f, 0.f, 0.f, 0.f};

    const int srow = tid >> 2;
    const int csrc = (tid & 3) ^ (srow & 3);

    for (int k0 = 0; k0 < EMB; k0 += 32) {
        #pragma unroll
        for (int s = 0; s < 2; ++s) {
            const int row = s * 64 + srow;
            gl_lds16(ab + (size_t)(row0 + row) * EMB + k0 + csrc * 8,
                     As + s * 2048 + w * 512);
            gl_lds16(wot + (size_t)(col0 + row) * EMB + k0 + csrc * 8,
                     Bs + s * 2048 + w * 512);
        }
        __syncthreads();
        short8 af[4], bf[4];
        #pragma unroll
        for (int mt = 0; mt < 4; ++mt) {
            const int rm = wq * 64 + mt * 16 + l16;
            af[mt] = *(const short8*)(As + rm * 32 + ((quad ^ (rm & 3)) * 8));
        }
        #pragma unroll
        for (int nt = 0; nt < 4; ++nt) {
            const int rn = wn * 64 + nt * 16 + l16;
            bf[nt] = *(const short8*)(Bs + rn * 32 + ((quad ^ (rn & 3)) * 8));
        }
        #pragma unroll
        for (int mt = 0; mt < 4; ++mt)
            #pragma unroll
            for (int nt = 0; nt < 4; ++nt)
                acc[mt][nt] = __builtin_amdgcn_mfma_f32_16x16x32_bf16(af[mt], bf[nt], acc[mt][nt], 0, 0, 0);
        __syncthreads();
    }

    #pragma unroll
    for (int nt = 0; nt < 4; ++nt) {
        const int col_g = col0 + wn * 64 + nt * 16 + l16;
        const float bz = bias[col_g];
        #pragma unroll
        for (int mt = 0; mt < 4; ++mt) {
            #pragma unroll
            for (int i = 0; i < 4; ++i) {
                const int row_g = row0 + wq * 64 + mt * 16 + quad * 4 + i;
                out[(size_t)row_g * EMB + col_g] = acc[mt][nt][i] + bz;
            }
        }
    }
}

// ---------------------------------------------------------------------------
extern "C" void kernel_launch(void* const* d_in, const int* in_sizes, int n_in,
                              void* d_out, int out_size, void* d_ws, size_t ws_size,
                              hipStream_t stream) {
    const float* x    = (const float*)d_in[0];
    const void*  mask = d_in[1];
    const float* Wqkv = (const float*)d_in[2];
    const float* bqkv = (const float*)d_in[3];
    const float* Wout = (const float*)d_in[4];
    const float* bout = (const float*)d_in[5];
    float* out = (float*)d_out;

    ushort_t* xb  = (ushort_t*)d_ws;                 // [16384][512]
    ushort_t* wqt = xb + (size_t)MROWS * EMB;        // [1536][512]
    ushort_t* wot = wqt + (size_t)1536 * EMB;        // [512][512]
    ushort_t* qb  = wot + (size_t)EMB * EMB;         // [BH][N][DH]
    ushort_t* kb  = qb + QKV_ELEMS;
    ushort_t* vt  = kb + QKV_ELEMS;                  // [BH][DH][N]
    ushort_t* ab  = vt + QKV_ELEMS;                  // [B][N][EMB]
    float*    pmf = (float*)(ab + (size_t)MROWS * EMB); // f32 [B][SEQ]
    float*    mkl = pmf + (size_t)BB * SEQ;             // f32 [B][SEQ]
    float*    zrw = mkl + (size_t)BB * SEQ;             // f32 [SEQ]

    prep<<<dim3(PREP_TOTAL), 256, 0, stream>>>(x, mask, Wqkv, Wout, xb, pmf, mkl, zrw, wqt, wot);
    qkv_mfma<<<dim3(1536 / 128, MROWS / 128), 256, 0, stream>>>(xb, wqt, bqkv, qb, kb, vt);
    attn_mfma<<<dim3(NBH * (SEQ / 128)), 256, 0, stream>>>(qb, kb, vt, pmf, mkl, ab);
    out_mfma<<<dim3(EMB / 128, MROWS / 128), 256, 0, stream>>>(ab, wot, bout, out);
}

// Round 8
// 248.925 us; speedup vs baseline: 2.7197x; 1.0948x over previous
//
#include <hip/hip_runtime.h>
#include <math.h>

#define BB  8
#define SEQ 2048
#define EMB 512
#define NH  8
#define DH  64
#define NBH (BB * NH)                      // 64
#define MROWS (BB * SEQ)                   // 16384
#define QKV_ELEMS ((size_t)NBH * SEQ * DH) // 8388608
#define MASK_ELEMS (BB * (SEQ - 1))        // 16376
// 512^-0.5 * log2(e): q pre-scaled so softmax uses exp2 directly
#define QSCALE 0.06375871307545f

typedef __attribute__((ext_vector_type(8)))  short short8;
typedef __attribute__((ext_vector_type(4)))  float float4e;
typedef __attribute__((ext_vector_type(16))) float float16e;
typedef __attribute__((ext_vector_type(4)))  unsigned int uint4e;
typedef __attribute__((ext_vector_type(2)))  unsigned int uint2e;
typedef unsigned short ushort_t;

static __device__ inline unsigned short f2bf(float f) {
    unsigned int u = __float_as_uint(f);
    unsigned int r = (u + 0x7fffu + ((u >> 16) & 1u)) >> 16;
    return (unsigned short)r;
}

static __device__ inline void gl_lds16(const unsigned short* g, unsigned short* l) {
    __builtin_amdgcn_global_load_lds(
        (const __attribute__((address_space(1))) void*)g,
        (__attribute__((address_space(3))) void*)l, 16, 0, 0);
}

// ---------------------------------------------------------------------------
// Fused prep: one launch, blockIdx-partitioned.
//   [0, 8192)        conv_x : x fp32 -> xb bf16
//   [8192, 8256)     decode_mask -> pmf f32 [B][SEQ] (1/0, CLS=1),
//                    mkl f32 [B][SEQ] (0 / -1e9), zrow f32 [SEQ] (zeros)
//   [8256, 9024)     wtrans Wqkv -> wqt bf16 [1536][512]
//   [9024, 9280)     wtrans Wout -> wot bf16 [512][512]
// ---------------------------------------------------------------------------
#define PREP_CONV   8192
#define PREP_MASK   (PREP_CONV + 64)
#define PREP_WQ     (PREP_MASK + (1536 / 32) * (EMB / 32))
#define PREP_TOTAL  (PREP_WQ + (EMB / 32) * (EMB / 32))

__global__ __launch_bounds__(256) void prep(const float* __restrict__ x,
                                            const void* __restrict__ mraw,
                                            const float* __restrict__ Wqkv,
                                            const float* __restrict__ Wout,
                                            ushort_t* __restrict__ xb,
                                            float* __restrict__ pmf,
                                            float* __restrict__ mkl,
                                            float* __restrict__ zrow,
                                            ushort_t* __restrict__ wqt,
                                            ushort_t* __restrict__ wot) {
    __shared__ float T[32][33];
    __shared__ int flag;
    const int bid = blockIdx.x;
    const int tid = threadIdx.x;

    if (bid < PREP_CONV) {
        const size_t i = ((size_t)bid * 256 + tid) * 4;
        float4 v = *(const float4*)&x[i];
        ushort4 o;
        o.x = f2bf(v.x); o.y = f2bf(v.y); o.z = f2bf(v.z); o.w = f2bf(v.w);
        *(ushort4*)&xb[i] = o;
    } else if (bid < PREP_MASK) {
        if (tid == 0) flag = 0;
        __syncthreads();
        const unsigned int* mi = (const unsigned int*)mraw;
        int local = 0;
        for (int i = tid; i < MASK_ELEMS / 4; i += 256) {
            if (mi[i] > 1u) local = 1;
        }
        if (local) flag = 1;
        __syncthreads();
        const int isbyte = flag;
        const unsigned char* mb = (const unsigned char*)mraw;
        const int* m32 = (const int*)mraw;
        const int i = (bid - PREP_CONV) * 256 + tid;
        const int b = i >> 11, n = i & (SEQ - 1);
        int v;
        if (n == 0) v = 1;
        else {
            const int src = b * (SEQ - 1) + n - 1;
            v = isbyte ? (int)mb[src] : (m32[src] != 0 ? 1 : 0);
        }
        pmf[i] = v ? 1.0f : 0.0f;
        mkl[i] = v ? 0.0f : -1e9f;
        if (i < SEQ) zrow[i] = 0.0f;
    } else {
        const float* src;
        ushort_t* dst;
        int N, idx;
        if (bid < PREP_WQ) {
            src = Wqkv; dst = wqt; N = 1536; idx = bid - PREP_MASK;
        } else {
            src = Wout; dst = wot; N = EMB; idx = bid - PREP_WQ;
        }
        const int nb = N / 32;
        const int n0 = (idx % nb) * 32;
        const int k0 = (idx / nb) * 32;
        {
            const int r = tid >> 3, c4 = (tid & 7) * 4;
            *(float4*)&T[r][c4] = *(const float4*)&src[(size_t)(k0 + r) * N + n0 + c4];
        }
        __syncthreads();
        const int n = tid >> 3, k4 = (tid & 7) * 4;
        ushort4 hv;
        hv.x = f2bf(T[k4 + 0][n]);
        hv.y = f2bf(T[k4 + 1][n]);
        hv.z = f2bf(T[k4 + 2][n]);
        hv.w = f2bf(T[k4 + 3][n]);
        *(ushort4*)&dst[(size_t)(n0 + n) * EMB + k0 + k4] = hv;
    }
}

// ---------------------------------------------------------------------------
// MFMA GEMM 1 (v2): qkv = xb @ WqkvT + bqkv.
//   BK=64 (half the barriers of BK=32; 32KB LDS, still 4 blocks/CU) and
//   XCD-ownership grid swizzle: XCD c owns M-panels [c*16, c*16+16) x all 12
//   N-blocks, so each 128-row A-panel (128KB) is fetched into exactly ONE
//   XCD L2 and reused by its 12 N-blocks (was: panel spread over ~8 XCDs ->
//   A re-fetched ~8x from HBM).
//   q -> qb [BH][N][DH] (pre-scaled by QSCALE), k -> kb, v -> vt [BH][DH][N].
// ---------------------------------------------------------------------------
__global__ __launch_bounds__(256) void qkv_mfma(const ushort_t* __restrict__ xb,
                                                const ushort_t* __restrict__ wt,
                                                const float* __restrict__ bias,
                                                ushort_t* __restrict__ qb,
                                                ushort_t* __restrict__ kb,
                                                ushort_t* __restrict__ vt) {
    __shared__ __align__(16) ushort_t As[128 * 64];   // 16KB
    __shared__ __align__(16) ushort_t Bs[128 * 64];   // 16KB
    const int tid  = threadIdx.x;
    const int w    = tid >> 6;
    const int lane = tid & 63;
    const int l16  = lane & 15;
    const int quad = lane >> 4;
    const int wq   = w >> 1;
    const int wn   = w & 1;
    // XCD-swizzled 1D grid (1536 blocks): c = XCD, r/12 = local M-panel.
    const int bid  = blockIdx.x;
    const int c    = bid & 7;
    const int r    = bid >> 3;            // 0..191
    const int mloc = r / 12;
    const int nblk = r - mloc * 12;
    const int row0 = (c * 16 + mloc) * 128;
    const int col0 = nblk * 128;

    float4e acc[4][4];
    #pragma unroll
    for (int i = 0; i < 4; ++i)
        #pragma unroll
        for (int j = 0; j < 4; ++j) acc[i][j] = (float4e){0.f, 0.f, 0.f, 0.f};

    // staging: 128 rows x 64 cols = 1024 chunks of 8 ushorts per matrix;
    // thread -> 4 chunks each: srow = tid>>3 (32-row groups s=0..3),
    // slot tid&7, XOR-swizzled source chunk csrc = (tid&7)^(srow&7).
    const int srow = tid >> 3;
    const int csrc = (tid & 7) ^ (srow & 7);

    for (int k0 = 0; k0 < EMB; k0 += 64) {
        #pragma unroll
        for (int s = 0; s < 4; ++s) {
            const int row = s * 32 + srow;
            gl_lds16(xb + (size_t)(row0 + row) * EMB + k0 + csrc * 8,
                     As + s * 2048 + w * 512);
            gl_lds16(wt + (size_t)(col0 + row) * EMB + k0 + csrc * 8,
                     Bs + s * 2048 + w * 512);
        }
        __syncthreads();
        #pragma unroll
        for (int kk = 0; kk < 2; ++kk) {
            short8 af[4], bf[4];
            #pragma unroll
            for (int mt = 0; mt < 4; ++mt) {
                const int rm = wq * 64 + mt * 16 + l16;
                af[mt] = *(const short8*)(As + rm * 64 + (((kk * 4 + quad) ^ (rm & 7)) * 8));
            }
            #pragma unroll
            for (int nt = 0; nt < 4; ++nt) {
                const int rn = wn * 64 + nt * 16 + l16;
                bf[nt] = *(const short8*)(Bs + rn * 64 + (((kk * 4 + quad) ^ (rn & 7)) * 8));
            }
            #pragma unroll
            for (int mt = 0; mt < 4; ++mt)
                #pragma unroll
                for (int nt = 0; nt < 4; ++nt)
                    acc[mt][nt] = __builtin_amdgcn_mfma_f32_16x16x32_bf16(af[mt], bf[nt], acc[mt][nt], 0, 0, 0);
        }
        __syncthreads();
    }

    #pragma unroll
    for (int nt = 0; nt < 4; ++nt) {
        const int cb    = col0 + wn * 64 + nt * 16;
        const int which = cb >> 9;
        const int h     = (cb >> 6) & 7;
        const int dcol  = (cb & 63) + l16;
        const float bz  = bias[cb + l16];
        if (which == 2) {
            #pragma unroll
            for (int mt = 0; mt < 4; ++mt) {
                const int rg = row0 + wq * 64 + mt * 16 + quad * 4;
                const int b = rg >> 11, n = rg & (SEQ - 1);
                ushort4 ov;
                ov.x = f2bf(acc[mt][nt][0] + bz);
                ov.y = f2bf(acc[mt][nt][1] + bz);
                ov.z = f2bf(acc[mt][nt][2] + bz);
                ov.w = f2bf(acc[mt][nt][3] + bz);
                *(ushort4*)&vt[((size_t)(b * NH + h) * DH + dcol) * SEQ + n] = ov;
            }
        } else {
            ushort_t* base = (which == 0) ? qb : kb;
            const float sc = (which == 0) ? QSCALE : 1.0f;
            #pragma unroll
            for (int mt = 0; mt < 4; ++mt) {
                #pragma unroll
                for (int i = 0; i < 4; ++i) {
                    const int rg = row0 + wq * 64 + mt * 16 + quad * 4 + i;
                    const int b = rg >> 11;
                    const int n = rg & (SEQ - 1);
                    base[((size_t)(b * NH + h) * SEQ + n) * DH + dcol] =
                        f2bf((acc[mt][nt][i] + bz) * sc);
                }
            }
        }
    }
}

// ---------------------------------------------------------------------------
// MFMA flash attention v10 (R4 verbatim — best measured: 109.5us).
//   K AND V staged in LDS dbuf; 2 waves/block, 64 q per wave (2 chains);
//   C-init mask fold (st starts at mkl 0/-1e9 -> p = exp2(st));
//   permlane32_swap half-wave P exchange; XCD swizzle + setprio.
//   Plateau note: 5 structural variants (R0/R1/R4/R5/R7) all land 109-132us
//   with every pipe <45% — locally converged.
// ---------------------------------------------------------------------------
__device__ inline void stage_tile(const ushort_t* kbh, const ushort_t* vbh, int kt,
                                  ushort_t* Kd, ushort_t* Vd,
                                  const int* crow, const int* csoff, int wbase) {
    #pragma unroll
    for (int j = 0; j < 4; ++j) {
        gl_lds16(kbh + (size_t)(kt * 64 + crow[j]) * DH + csoff[j],
                 Kd + (j * 128 + wbase) * 8);
        gl_lds16(vbh + (size_t)crow[j] * SEQ + kt * 64 + csoff[j],
                 Vd + (j * 128 + wbase) * 8);
    }
}

__global__ __launch_bounds__(128, 2) void attn_mfma(const ushort_t* __restrict__ qb,
                                                    const ushort_t* __restrict__ kb,
                                                    const ushort_t* __restrict__ vt,
                                                    const float* __restrict__ pmf,
                                                    const float* __restrict__ mkl,
                                                    const float* __restrict__ zrow,
                                                    ushort_t* __restrict__ ab) {
    __shared__ __align__(16) ushort_t Ks[2][64 * 64];   // 16KB (dbuf)
    __shared__ __align__(16) ushort_t Vts[2][64 * 64];  // 16KB (dbuf)
    __shared__ float lw[2][64];

    const int tid = threadIdx.x;
    const int w   = tid >> 6;          // 0,1
    const int lane = tid & 63;
    const int l5  = lane & 31;
    const int h   = lane >> 5;         // half-wave
    // XCD swizzle: xcd = bid&7 gets bh in [xcd*8, xcd*8+8) -> 4MB K+V per L2.
    const int bid = blockIdx.x;        // 0..1023
    const int ord = bid >> 3;          // 0..127
    const int bh  = (bid & 7) * 8 + (ord >> 4);
    const int qt  = ord & 15;
    const int b   = bh >> 3;
    const int hh  = bh & 7;
    const int q0  = qt * 128 + w * 64; // wave's first q row

    // Q fragments (B-operand of S^T): n=q=l5, k=dh=kc*16+h*8+j
    const ushort_t* qbh = qb + (size_t)bh * SEQ * DH;
    short8 qf[2][4];
    #pragma unroll
    for (int t = 0; t < 2; ++t)
        #pragma unroll
        for (int kc = 0; kc < 4; ++kc)
            qf[t][kc] = *(const short8*)(qbh + (size_t)(q0 + t * 32 + l5) * DH + kc * 16 + h * 8);

    // q mask: masked-q chains get zeroed Q and read the zeros row as C-init,
    // so st = 0 -> p = 1 for every key (reference's uniform-softmax row).
    const float* crb[2];
    #pragma unroll
    for (int t = 0; t < 2; ++t) {
        const float mq = pmf[b * SEQ + q0 + t * 32 + l5];
        if (mq == 0.0f) {
            const short8 z8 = {0, 0, 0, 0, 0, 0, 0, 0};
            #pragma unroll
            for (int kc = 0; kc < 4; ++kc) qf[t][kc] = z8;
        }
        crb[t] = (mq != 0.0f) ? (mkl + b * SEQ) : zrow;
    }

    // staging chunk params: 512 chunks/tile, 128 thr -> 4 each; swizzle
    // ((c&7)^(row&7)) folded into the SOURCE column.
    int crow[4], csoff[4];
    #pragma unroll
    for (int j = 0; j < 4; ++j) {
        const int c = j * 128 + tid;
        crow[j]  = c >> 3;
        csoff[j] = ((c & 7) ^ (crow[j] & 7)) * 8;
    }
    const int wbase = w * 64;
    const ushort_t* kbh = kb + (size_t)bh * SEQ * DH;
    const ushort_t* vbh = vt + (size_t)bh * DH * SEQ;

    float16e o[2][2];   // [t][dh-tile]
    #pragma unroll
    for (int t = 0; t < 2; ++t)
        #pragma unroll
        for (int d = 0; d < 2; ++d) o[t][d] = (float16e)0.0f;
    float l_i[2] = {0.f, 0.f};

    stage_tile(kbh, vbh, 0, Ks[0], Vts[0], crow, csoff, wbase);

    for (int kt = 0; kt < 32; ++kt) {
        __syncthreads();   // staged tile visible; drain covered by prev compute
        const int cur = kt & 1;
        if (kt < 31)
            stage_tile(kbh, vbh, kt + 1, Ks[cur ^ 1], Vts[cur ^ 1], crow, csoff, wbase);

        #pragma unroll
        for (int s = 0; s < 2; ++s) {
            // ---- C-init: mask logits (0 valid / -1e9 masked), L1-hot ----
            // reg r -> key (r&3)+8*(r>>2)+4h (+s*32)
            float16e st[2];
            #pragma unroll
            for (int t = 0; t < 2; ++t) {
                #pragma unroll
                for (int g2 = 0; g2 < 4; ++g2) {
                    const float4e c4 = *(const float4e*)(crb[t] + kt * 64 + s * 32 + g2 * 8 + h * 4);
                    #pragma unroll
                    for (int j = 0; j < 4; ++j)
                        st[t][g2 * 4 + j] = c4[j];
                }
            }

            // ---- S^T = K·Q per 32-key tile (A=K, B=Q) ----
            const int krow = s * 32 + l5;
            short8 kf[4];
            #pragma unroll
            for (int kc = 0; kc < 4; ++kc)
                kf[kc] = *(const short8*)(Ks[cur] + krow * 64 + (((kc * 2 + h) ^ (krow & 7)) * 8));
            __builtin_amdgcn_s_setprio(1);
            #pragma unroll
            for (int kc = 0; kc < 4; ++kc) {
                st[0] = __builtin_amdgcn_mfma_f32_32x32x16_bf16(kf[kc], qf[0][kc], st[0], 0, 0, 0);
                st[1] = __builtin_amdgcn_mfma_f32_32x32x16_bf16(kf[kc], qf[1][kc], st[1], 0, 0, 0);
            }
            __builtin_amdgcn_s_setprio(0);

            // ---- softmax: p = exp2(st) (mask already in st); pack bf16
            // pairs; half-wave exchange via permlane32_swap -> PV A-frags ----
            short8 af[2][2];
            #pragma unroll
            for (int t = 0; t < 2; ++t) {
                unsigned int a[8];
                float lacc = 0.f;
                #pragma unroll
                for (int j = 0; j < 8; ++j) {
                    const float p0 = __builtin_amdgcn_exp2f(st[t][2 * j]);
                    const float p1 = __builtin_amdgcn_exp2f(st[t][2 * j + 1]);
                    lacc += p0 + p1;
                    a[j] = (__float_as_uint(p0) >> 16) | (__float_as_uint(p1) & 0xffff0000u);
                }
                l_i[t] += lacc;
                #pragma unroll
                for (int c = 0; c < 2; ++c) {
                    const uint2e r02 = __builtin_amdgcn_permlane32_swap(a[4 * c],     a[4 * c + 2], false, false);
                    const uint2e r13 = __builtin_amdgcn_permlane32_swap(a[4 * c + 1], a[4 * c + 3], false, false);
                    uint4e fv;
                    fv.x = r02[0];
                    fv.y = r13[0];
                    fv.z = r02[1];
                    fv.w = r13[1];
                    af[t][c] = __builtin_bit_cast(short8, fv);
                }
            }

            // ---- PV: O[t][d] += P @ V (A=P regs, B=V from LDS) ----
            __builtin_amdgcn_s_setprio(1);
            #pragma unroll
            for (int c = 0; c < 2; ++c) {
                #pragma unroll
                for (int d = 0; d < 2; ++d) {
                    const int vrow = d * 32 + l5;
                    const short8 vf = *(const short8*)(Vts[cur] + vrow * 64 +
                                       (((s * 4 + c * 2 + h) ^ (vrow & 7)) * 8));
                    o[0][d] = __builtin_amdgcn_mfma_f32_32x32x16_bf16(af[0][c], vf, o[0][d], 0, 0, 0);
                    o[1][d] = __builtin_amdgcn_mfma_f32_32x32x16_bf16(af[1][c], vf, o[1][d], 0, 0, 0);
                }
            }
            __builtin_amdgcn_s_setprio(0);
        }
    }

    // l: each half-wave holds its 32-key partials; combine across halves
    #pragma unroll
    for (int t = 0; t < 2; ++t) {
        const float l = l_i[t] + __shfl_xor(l_i[t], 32);
        lw[w][t * 32 + l5] = l;   // both halves write same value
    }

    ushort_t* ob = ab + ((size_t)b * SEQ + q0) * EMB + hh * DH;
    #pragma unroll
    for (int t = 0; t < 2; ++t) {
        #pragma unroll
        for (int r = 0; r < 16; ++r) {
            const int ql = (r & 3) + 8 * (r >> 2) + 4 * h;
            const float inv = 1.0f / lw[w][t * 32 + ql];
            #pragma unroll
            for (int d = 0; d < 2; ++d)
                ob[(size_t)(t * 32 + ql) * EMB + d * 32 + l5] = f2bf(o[t][d][r] * inv);
        }
    }
}

// ---------------------------------------------------------------------------
// MFMA GEMM 2 (v2): out = ab @ WoutT + bout (fp32 out).
//   Same BK=64 + XCD-ownership swizzle as qkv (512 blocks: XCD c owns
//   M-panels [c*16, c*16+16) x 4 N-blocks).
// ---------------------------------------------------------------------------
__global__ __launch_bounds__(256) void out_mfma(const ushort_t* __restrict__ ab,
                                                const ushort_t* __restrict__ wot,
                                                const float* __restrict__ bias,
                                                float* __restrict__ out) {
    __shared__ __align__(16) ushort_t As[128 * 64];
    __shared__ __align__(16) ushort_t Bs[128 * 64];
    const int tid  = threadIdx.x;
    const int w    = tid >> 6;
    const int lane = tid & 63;
    const int l16  = lane & 15;
    const int quad = lane >> 4;
    const int wq   = w >> 1;
    const int wn   = w & 1;
    const int bid  = blockIdx.x;          // 0..511
    const int c    = bid & 7;
    const int r    = bid >> 3;            // 0..63
    const int mloc = r >> 2;
    const int nblk = r & 3;
    const int row0 = (c * 16 + mloc) * 128;
    const int col0 = nblk * 128;

    float4e acc[4][4];
    #pragma unroll
    for (int i = 0; i < 4; ++i)
        #pragma unroll
        for (int j = 0; j < 4; ++j) acc[i][j] = (float4e){0.f, 0.f, 0.f, 0.f};

    const int srow = tid >> 3;
    const int csrc = (tid & 7) ^ (srow & 7);

    for (int k0 = 0; k0 < EMB; k0 += 64) {
        #pragma unroll
        for (int s = 0; s < 4; ++s) {
            const int row = s * 32 + srow;
            gl_lds16(ab + (size_t)(row0 + row) * EMB + k0 + csrc * 8,
                     As + s * 2048 + w * 512);
            gl_lds16(wot + (size_t)(col0 + row) * EMB + k0 + csrc * 8,
                     Bs + s * 2048 + w * 512);
        }
        __syncthreads();
        #pragma unroll
        for (int kk = 0; kk < 2; ++kk) {
            short8 af[4], bf[4];
            #pragma unroll
            for (int mt = 0; mt < 4; ++mt) {
                const int rm = wq * 64 + mt * 16 + l16;
                af[mt] = *(const short8*)(As + rm * 64 + (((kk * 4 + quad) ^ (rm & 7)) * 8));
            }
            #pragma unroll
            for (int nt = 0; nt < 4; ++nt) {
                const int rn = wn * 64 + nt * 16 + l16;
                bf[nt] = *(const short8*)(Bs + rn * 64 + (((kk * 4 + quad) ^ (rn & 7)) * 8));
            }
            #pragma unroll
            for (int mt = 0; mt < 4; ++mt)
                #pragma unroll
                for (int nt = 0; nt < 4; ++nt)
                    acc[mt][nt] = __builtin_amdgcn_mfma_f32_16x16x32_bf16(af[mt], bf[nt], acc[mt][nt], 0, 0, 0);
        }
        __syncthreads();
    }

    #pragma unroll
    for (int nt = 0; nt < 4; ++nt) {
        const int col_g = col0 + wn * 64 + nt * 16 + l16;
        const float bz = bias[col_g];
        #pragma unroll
        for (int mt = 0; mt < 4; ++mt) {
            #pragma unroll
            for (int i = 0; i < 4; ++i) {
                const int row_g = row0 + wq * 64 + mt * 16 + quad * 4 + i;
                out[(size_t)row_g * EMB + col_g] = acc[mt][nt][i] + bz;
            }
        }
    }
}

// ---------------------------------------------------------------------------
extern "C" void kernel_launch(void* const* d_in, const int* in_sizes, int n_in,
                              void* d_out, int out_size, void* d_ws, size_t ws_size,
                              hipStream_t stream) {
    const float* x    = (const float*)d_in[0];
    const void*  mask = d_in[1];
    const float* Wqkv = (const float*)d_in[2];
    const float* bqkv = (const float*)d_in[3];
    const float* Wout = (const float*)d_in[4];
    const float* bout = (const float*)d_in[5];
    float* out = (float*)d_out;

    ushort_t* xb  = (ushort_t*)d_ws;                 // [16384][512]
    ushort_t* wqt = xb + (size_t)MROWS * EMB;        // [1536][512]
    ushort_t* wot = wqt + (size_t)1536 * EMB;        // [512][512]
    ushort_t* qb  = wot + (size_t)EMB * EMB;         // [BH][N][DH]
    ushort_t* kb  = qb + QKV_ELEMS;
    ushort_t* vt  = kb + QKV_ELEMS;                  // [BH][DH][N]
    ushort_t* ab  = vt + QKV_ELEMS;                  // [B][N][EMB]
    float*    pmf = (float*)(ab + (size_t)MROWS * EMB); // f32 [B][SEQ]
    float*    mkl = pmf + (size_t)BB * SEQ;             // f32 [B][SEQ]
    float*    zrw = mkl + (size_t)BB * SEQ;             // f32 [SEQ]

    prep<<<dim3(PREP_TOTAL), 256, 0, stream>>>(x, mask, Wqkv, Wout, xb, pmf, mkl, zrw, wqt, wot);
    qkv_mfma<<<dim3(1536), 256, 0, stream>>>(xb, wqt, bqkv, qb, kb, vt);
    attn_mfma<<<dim3(NBH * (SEQ / 128)), 128, 0, stream>>>(qb, kb, vt, pmf, mkl, zrw, ab);
    out_mfma<<<dim3(512), 256, 0, stream>>>(ab, wot, bout, out);
}

// Round 9
// 247.137 us; speedup vs baseline: 2.7393x; 1.0072x over previous
//
#include <hip/hip_runtime.h>
#include <math.h>

#define BB  8
#define SEQ 2048
#define EMB 512
#define NH  8
#define DH  64
#define NBH (BB * NH)                      // 64
#define MROWS (BB * SEQ)                   // 16384
#define QKV_ELEMS ((size_t)NBH * SEQ * DH) // 8388608
#define MASK_ELEMS (BB * (SEQ - 1))        // 16376
// 512^-0.5 * log2(e): q pre-scaled so softmax uses exp2 directly
#define QSCALE 0.06375871307545f

typedef __attribute__((ext_vector_type(8)))  short short8;
typedef __attribute__((ext_vector_type(4)))  float float4e;
typedef __attribute__((ext_vector_type(16))) float float16e;
typedef __attribute__((ext_vector_type(4)))  unsigned int uint4e;
typedef __attribute__((ext_vector_type(2)))  unsigned int uint2e;
typedef unsigned short ushort_t;

static __device__ inline unsigned short f2bf(float f) {
    unsigned int u = __float_as_uint(f);
    unsigned int r = (u + 0x7fffu + ((u >> 16) & 1u)) >> 16;
    return (unsigned short)r;
}

static __device__ inline void gl_lds16(const unsigned short* g, unsigned short* l) {
    __builtin_amdgcn_global_load_lds(
        (const __attribute__((address_space(1))) void*)g,
        (__attribute__((address_space(3))) void*)l, 16, 0, 0);
}

// ---------------------------------------------------------------------------
// Fused prep: one launch, blockIdx-partitioned.
//   [0, 8192)        conv_x : x fp32 -> xb bf16
//   [8192, 8256)     decode_mask -> pmf f32 [B][SEQ] (1/0, CLS=1) and
//                    pmb u32 [B][SEQ/32] key-valid bitmask (ballot)
//   [8256, 9024)     wtrans Wqkv -> wqt bf16 [1536][512]
//   [9024, 9280)     wtrans Wout -> wot bf16 [512][512]
// ---------------------------------------------------------------------------
#define PREP_CONV   8192
#define PREP_MASK   (PREP_CONV + 64)
#define PREP_WQ     (PREP_MASK + (1536 / 32) * (EMB / 32))
#define PREP_TOTAL  (PREP_WQ + (EMB / 32) * (EMB / 32))

__global__ __launch_bounds__(256) void prep(const float* __restrict__ x,
                                            const void* __restrict__ mraw,
                                            const float* __restrict__ Wqkv,
                                            const float* __restrict__ Wout,
                                            ushort_t* __restrict__ xb,
                                            float* __restrict__ pmf,
                                            unsigned* __restrict__ pmb,
                                            ushort_t* __restrict__ wqt,
                                            ushort_t* __restrict__ wot) {
    __shared__ float T[32][33];
    __shared__ int flag;
    const int bid = blockIdx.x;
    const int tid = threadIdx.x;

    if (bid < PREP_CONV) {
        const size_t i = ((size_t)bid * 256 + tid) * 4;
        float4 v = *(const float4*)&x[i];
        ushort4 o;
        o.x = f2bf(v.x); o.y = f2bf(v.y); o.z = f2bf(v.z); o.w = f2bf(v.w);
        *(ushort4*)&xb[i] = o;
    } else if (bid < PREP_MASK) {
        if (tid == 0) flag = 0;
        __syncthreads();
        const unsigned int* mi = (const unsigned int*)mraw;
        int local = 0;
        for (int i = tid; i < MASK_ELEMS / 4; i += 256) {
            if (mi[i] > 1u) local = 1;
        }
        if (local) flag = 1;
        __syncthreads();
        const int isbyte = flag;
        const unsigned char* mb = (const unsigned char*)mraw;
        const int* m32 = (const int*)mraw;
        const int i = (bid - PREP_CONV) * 256 + tid;
        const int b = i >> 11, n = i & (SEQ - 1);
        int v;
        if (n == 0) v = 1;
        else {
            const int src = b * (SEQ - 1) + n - 1;
            v = isbyte ? (int)mb[src] : (m32[src] != 0 ? 1 : 0);
        }
        pmf[i] = v ? 1.0f : 0.0f;
        // key-valid bitmask: wave = 64 consecutive n (never crosses b)
        const unsigned long long bl = __ballot(v);
        if ((tid & 31) == 0) pmb[i >> 5] = (unsigned)(bl >> (tid & 32));
    } else {
        const float* src;
        ushort_t* dst;
        int N, idx;
        if (bid < PREP_WQ) {
            src = Wqkv; dst = wqt; N = 1536; idx = bid - PREP_MASK;
        } else {
            src = Wout; dst = wot; N = EMB; idx = bid - PREP_WQ;
        }
        const int nb = N / 32;
        const int n0 = (idx % nb) * 32;
        const int k0 = (idx / nb) * 32;
        {
            const int r = tid >> 3, c4 = (tid & 7) * 4;
            *(float4*)&T[r][c4] = *(const float4*)&src[(size_t)(k0 + r) * N + n0 + c4];
        }
        __syncthreads();
        const int n = tid >> 3, k4 = (tid & 7) * 4;
        ushort4 hv;
        hv.x = f2bf(T[k4 + 0][n]);
        hv.y = f2bf(T[k4 + 1][n]);
        hv.z = f2bf(T[k4 + 2][n]);
        hv.w = f2bf(T[k4 + 3][n]);
        *(ushort4*)&dst[(size_t)(n0 + n) * EMB + k0 + k4] = hv;
    }
}

// ---------------------------------------------------------------------------
// MFMA GEMM 1 (v2): qkv = xb @ WqkvT + bqkv. BK=64 + XCD-ownership swizzle.
//   q -> qb [BH][N][DH] (pre-scaled by QSCALE), k -> kb, v -> vt [BH][DH][N].
// ---------------------------------------------------------------------------
__global__ __launch_bounds__(256) void qkv_mfma(const ushort_t* __restrict__ xb,
                                                const ushort_t* __restrict__ wt,
                                                const float* __restrict__ bias,
                                                ushort_t* __restrict__ qb,
                                                ushort_t* __restrict__ kb,
                                                ushort_t* __restrict__ vt) {
    __shared__ __align__(16) ushort_t As[128 * 64];   // 16KB
    __shared__ __align__(16) ushort_t Bs[128 * 64];   // 16KB
    const int tid  = threadIdx.x;
    const int w    = tid >> 6;
    const int lane = tid & 63;
    const int l16  = lane & 15;
    const int quad = lane >> 4;
    const int wq   = w >> 1;
    const int wn   = w & 1;
    const int bid  = blockIdx.x;
    const int c    = bid & 7;
    const int r    = bid >> 3;            // 0..191
    const int mloc = r / 12;
    const int nblk = r - mloc * 12;
    const int row0 = (c * 16 + mloc) * 128;
    const int col0 = nblk * 128;

    float4e acc[4][4];
    #pragma unroll
    for (int i = 0; i < 4; ++i)
        #pragma unroll
        for (int j = 0; j < 4; ++j) acc[i][j] = (float4e){0.f, 0.f, 0.f, 0.f};

    const int srow = tid >> 3;
    const int csrc = (tid & 7) ^ (srow & 7);

    for (int k0 = 0; k0 < EMB; k0 += 64) {
        #pragma unroll
        for (int s = 0; s < 4; ++s) {
            const int row = s * 32 + srow;
            gl_lds16(xb + (size_t)(row0 + row) * EMB + k0 + csrc * 8,
                     As + s * 2048 + w * 512);
            gl_lds16(wt + (size_t)(col0 + row) * EMB + k0 + csrc * 8,
                     Bs + s * 2048 + w * 512);
        }
        __syncthreads();
        #pragma unroll
        for (int kk = 0; kk < 2; ++kk) {
            short8 af[4], bf[4];
            #pragma unroll
            for (int mt = 0; mt < 4; ++mt) {
                const int rm = wq * 64 + mt * 16 + l16;
                af[mt] = *(const short8*)(As + rm * 64 + (((kk * 4 + quad) ^ (rm & 7)) * 8));
            }
            #pragma unroll
            for (int nt = 0; nt < 4; ++nt) {
                const int rn = wn * 64 + nt * 16 + l16;
                bf[nt] = *(const short8*)(Bs + rn * 64 + (((kk * 4 + quad) ^ (rn & 7)) * 8));
            }
            #pragma unroll
            for (int mt = 0; mt < 4; ++mt)
                #pragma unroll
                for (int nt = 0; nt < 4; ++nt)
                    acc[mt][nt] = __builtin_amdgcn_mfma_f32_16x16x32_bf16(af[mt], bf[nt], acc[mt][nt], 0, 0, 0);
        }
        __syncthreads();
    }

    #pragma unroll
    for (int nt = 0; nt < 4; ++nt) {
        const int cb    = col0 + wn * 64 + nt * 16;
        const int which = cb >> 9;
        const int h     = (cb >> 6) & 7;
        const int dcol  = (cb & 63) + l16;
        const float bz  = bias[cb + l16];
        if (which == 2) {
            #pragma unroll
            for (int mt = 0; mt < 4; ++mt) {
                const int rg = row0 + wq * 64 + mt * 16 + quad * 4;
                const int b = rg >> 11, n = rg & (SEQ - 1);
                ushort4 ov;
                ov.x = f2bf(acc[mt][nt][0] + bz);
                ov.y = f2bf(acc[mt][nt][1] + bz);
                ov.z = f2bf(acc[mt][nt][2] + bz);
                ov.w = f2bf(acc[mt][nt][3] + bz);
                *(ushort4*)&vt[((size_t)(b * NH + h) * DH + dcol) * SEQ + n] = ov;
            }
        } else {
            ushort_t* base = (which == 0) ? qb : kb;
            const float sc = (which == 0) ? QSCALE : 1.0f;
            #pragma unroll
            for (int mt = 0; mt < 4; ++mt) {
                #pragma unroll
                for (int i = 0; i < 4; ++i) {
                    const int rg = row0 + wq * 64 + mt * 16 + quad * 4 + i;
                    const int b = rg >> 11;
                    const int n = rg & (SEQ - 1);
                    base[((size_t)(b * NH + h) * SEQ + n) * DH + dcol] =
                        f2bf((acc[mt][nt][i] + bz) * sc);
                }
            }
        }
    }
}

// ---------------------------------------------------------------------------
// MFMA flash attention v15: barrier-free wave-private pipeline (T4).
//   1-wave (64-thr) blocks, 64 q per wave (2 chains, R4-proven math).
//   KVBLK=32; wave-private K/V dbuf in 4 DISTINCT __shared__ objects
//   (16.6KB -> 9 blocks/CU; grid 2048 = 8/CU). NO __syncthreads anywhere:
//   ordering is a single counted s_waitcnt vmcnt(8) per kt -- the 8 staging
//   loads for kt+1 stay in flight across the whole compute of kt (m201/T4).
//   Masks are a bitmask (pmb): lane holds word lane for all 64 kts; per kt
//   one readlane + and/cndmask C-init -> ZERO per-kt VMEM besides staging
//   (removes the R5 FIFO-drain trap). kt=63 prefetches phantom kt=64 (lands
//   in d_ws, never read) so the loop is fully uniform.
// ---------------------------------------------------------------------------
__global__ __launch_bounds__(64, 2) void attn_mfma(const ushort_t* __restrict__ qb,
                                                   const ushort_t* __restrict__ kb,
                                                   const ushort_t* __restrict__ vt,
                                                   const float* __restrict__ pmf,
                                                   const unsigned* __restrict__ pmb,
                                                   ushort_t* __restrict__ ab) {
    __shared__ __align__(16) ushort_t Ks0[32 * 64];   // 4KB
    __shared__ __align__(16) ushort_t Vs0[64 * 32];   // 4KB
    __shared__ __align__(16) ushort_t Ks1[32 * 64];   // 4KB
    __shared__ __align__(16) ushort_t Vs1[64 * 32];   // 4KB
    __shared__ float lw[64];

    const int lane = threadIdx.x;      // one wave
    const int l5   = lane & 31;
    const int h    = lane >> 5;
    // XCD swizzle: xcd = bid&7 gets bh in [xcd*8, xcd*8+8) -> K+V L2-resident
    const int bid = blockIdx.x;        // 0..2047
    const int ord = bid >> 3;          // 0..255
    const int bh  = (bid & 7) * 8 + (ord >> 5);
    const int qt  = ord & 31;
    const int b   = bh >> 3;
    const int hh  = bh & 7;
    const int q0  = qt * 64;

    // Q fragments (B-operand of S^T): n=q=l5, k=dh=kc*16+h*8+j
    const ushort_t* qbh = qb + (size_t)bh * SEQ * DH;
    short8 qf[2][4];
    #pragma unroll
    for (int t = 0; t < 2; ++t)
        #pragma unroll
        for (int kc = 0; kc < 4; ++kc)
            qf[t][kc] = *(const short8*)(qbh + (size_t)(q0 + t * 32 + l5) * DH + kc * 16 + h * 8);

    // q mask: masked-q chains get zeroed Q and st-init 0 -> p=1 for all keys
    bool qv[2];
    #pragma unroll
    for (int t = 0; t < 2; ++t) {
        const float mq = pmf[b * SEQ + q0 + t * 32 + l5];
        qv[t] = (mq != 0.0f);
        if (!qv[t]) {
            const short8 z8 = {0, 0, 0, 0, 0, 0, 0, 0};
            #pragma unroll
            for (int kc = 0; kc < 4; ++kc) qf[t][kc] = z8;
        }
    }

    // key-valid bitmask: lane holds word 'lane' (keys lane*32..+31)
    const unsigned wm = pmb[b * 64 + lane];

    const ushort_t* kbh = kb + (size_t)bh * SEQ * DH;
    const ushort_t* vbh = vt + (size_t)bh * DH * SEQ;

    // lane-derived staging params (kt-independent)
    const int l3  = lane >> 3;
    const int c8  = (lane & 7) ^ (l3 & 7);     // K slot swizzle (8 slots)
    const int l2  = lane >> 2;
    const int c4v = (lane & 3) ^ (l2 & 3);     // V slot swizzle (4 slots)

    float16e o[2][2];
    #pragma unroll
    for (int t = 0; t < 2; ++t)
        #pragma unroll
        for (int d = 0; d < 2; ++d) o[t][d] = (float16e)0.0f;
    float l_i[2] = {0.f, 0.f};

    // K tile [32 keys][8 slots x 8us]; V tile [64 dh][4 slots x 8us]
    auto stage = [&](int kt, ushort_t* Kd, ushort_t* Vd) {
        #pragma unroll
        for (int j = 0; j < 4; ++j) {
            gl_lds16(kbh + (size_t)(kt * 32 + j * 8 + l3) * DH + c8 * 8, Kd + j * 512);
            gl_lds16(vbh + (size_t)(j * 16 + l2) * SEQ + kt * 32 + c4v * 8, Vd + j * 512);
        }
    };

    auto body = [&](int kt, const ushort_t* Kr, const ushort_t* Vr,
                    ushort_t* Kw, ushort_t* Vw) {
        // issue kt+1 staging first (phantom at kt=63: lands in d_ws, unread)
        stage(kt + 1, Kw, Vw);
        // wait kt's 8 loads (oldest); kt+1's 8 stay in flight (T4: never 0)
        asm volatile("s_waitcnt vmcnt(8)" ::: "memory");
        __builtin_amdgcn_sched_barrier(0);

        // ---- C-init from mask bits: reg r -> key (r&3)+8*(r>>2)+4h ----
        const unsigned mwf = (unsigned)__builtin_amdgcn_readlane((int)wm, kt);
        const unsigned mh  = h ? (mwf >> 4) : mwf;
        float16e st0, st1;
        #pragma unroll
        for (int j = 0; j < 16; ++j) {
            const float bv = (mh & (1u << ((j & 3) + 8 * (j >> 2)))) ? 0.0f : -1e9f;
            st0[j] = qv[0] ? bv : 0.0f;
            st1[j] = qv[1] ? bv : 0.0f;
        }

        // ---- S^T = K·Q (A=K from LDS, B=Q regs) ----
        short8 kf[4];
        #pragma unroll
        for (int kc = 0; kc < 4; ++kc)
            kf[kc] = *(const short8*)(Kr + l5 * 64 + (((kc * 2 + h) ^ (l5 & 7)) * 8));
        __builtin_amdgcn_s_setprio(1);
        #pragma unroll
        for (int kc = 0; kc < 4; ++kc) {
            st0 = __builtin_amdgcn_mfma_f32_32x32x16_bf16(kf[kc], qf[0][kc], st0, 0, 0, 0);
            st1 = __builtin_amdgcn_mfma_f32_32x32x16_bf16(kf[kc], qf[1][kc], st1, 0, 0, 0);
        }
        __builtin_amdgcn_s_setprio(0);

        // ---- softmax p = exp2(st); pack bf16 pairs; permlane32_swap ----
        short8 af[2][2];
        #pragma unroll
        for (int t = 0; t < 2; ++t) {
            const float16e& st = t ? st1 : st0;
            unsigned int a[8];
            float lacc = 0.f;
            #pragma unroll
            for (int j = 0; j < 8; ++j) {
                const float p0 = __builtin_amdgcn_exp2f(st[2 * j]);
                const float p1 = __builtin_amdgcn_exp2f(st[2 * j + 1]);
                lacc += p0 + p1;
                a[j] = (__float_as_uint(p0) >> 16) | (__float_as_uint(p1) & 0xffff0000u);
            }
            l_i[t] += lacc;
            #pragma unroll
            for (int c = 0; c < 2; ++c) {
                const uint2e r02 = __builtin_amdgcn_permlane32_swap(a[4 * c],     a[4 * c + 2], false, false);
                const uint2e r13 = __builtin_amdgcn_permlane32_swap(a[4 * c + 1], a[4 * c + 3], false, false);
                uint4e fv;
                fv.x = r02[0];
                fv.y = r13[0];
                fv.z = r02[1];
                fv.w = r13[1];
                af[t][c] = __builtin_bit_cast(short8, fv);
            }
        }

        // ---- PV: O[t][d] += P @ V (B=V from LDS, slot (c*2+h)^(vr&3)) ----
        __builtin_amdgcn_s_setprio(1);
        #pragma unroll
        for (int c = 0; c < 2; ++c) {
            #pragma unroll
            for (int d = 0; d < 2; ++d) {
                const int vr = d * 32 + l5;
                const short8 vf = *(const short8*)(Vr + vr * 32 +
                                   (((c * 2 + h) ^ (vr & 3)) * 8));
                o[0][d] = __builtin_amdgcn_mfma_f32_32x32x16_bf16(af[0][c], vf, o[0][d], 0, 0, 0);
                o[1][d] = __builtin_amdgcn_mfma_f32_32x32x16_bf16(af[1][c], vf, o[1][d], 0, 0, 0);
            }
        }
        __builtin_amdgcn_s_setprio(0);
    };

    stage(0, Ks0, Vs0);
    for (int kt2 = 0; kt2 < 64; kt2 += 2) {
        body(kt2,     Ks0, Vs0, Ks1, Vs1);
        body(kt2 + 1, Ks1, Vs1, Ks0, Vs0);
    }

    // l: combine across half-waves; single wave -> no barrier needed
    #pragma unroll
    for (int t = 0; t < 2; ++t) {
        const float l = l_i[t] + __shfl_xor(l_i[t], 32);
        lw[t * 32 + l5] = l;   // both halves write same value
    }

    ushort_t* ob = ab + ((size_t)b * SEQ + q0) * EMB + hh * DH;
    #pragma unroll
    for (int t = 0; t < 2; ++t) {
        #pragma unroll
        for (int r = 0; r < 16; ++r) {
            const int ql = (r & 3) + 8 * (r >> 2) + 4 * h;
            const float inv = 1.0f / lw[t * 32 + ql];
            #pragma unroll
            for (int d = 0; d < 2; ++d)
                ob[(size_t)(t * 32 + ql) * EMB + d * 32 + l5] = f2bf(o[t][d][r] * inv);
        }
    }
}

// ---------------------------------------------------------------------------
// MFMA GEMM 2 (v2): out = ab @ WoutT + bout (fp32 out). BK=64 + XCD swizzle.
// ---------------------------------------------------------------------------
__global__ __launch_bounds__(256) void out_mfma(const ushort_t* __restrict__ ab,
                                                const ushort_t* __restrict__ wot,
                                                const float* __restrict__ bias,
                                                float* __restrict__ out) {
    __shared__ __align__(16) ushort_t As[128 * 64];
    __shared__ __align__(16) ushort_t Bs[128 * 64];
    const int tid  = threadIdx.x;
    const int w    = tid >> 6;
    const int lane = tid & 63;
    const int l16  = lane & 15;
    const int quad = lane >> 4;
    const int wq   = w >> 1;
    const int wn   = w & 1;
    const int bid  = blockIdx.x;          // 0..511
    const int c    = bid & 7;
    const int r    = bid >> 3;            // 0..63
    const int mloc = r >> 2;
    const int nblk = r & 3;
    const int row0 = (c * 16 + mloc) * 128;
    const int col0 = nblk * 128;

    float4e acc[4][4];
    #pragma unroll
    for (int i = 0; i < 4; ++i)
        #pragma unroll
        for (int j = 0; j < 4; ++j) acc[i][j] = (float4e){0.f, 0.f, 0.f, 0.f};

    const int srow = tid >> 3;
    const int csrc = (tid & 7) ^ (srow & 7);

    for (int k0 = 0; k0 < EMB; k0 += 64) {
        #pragma unroll
        for (int s = 0; s < 4; ++s) {
            const int row = s * 32 + srow;
            gl_lds16(ab + (size_t)(row0 + row) * EMB + k0 + csrc * 8,
                     As + s * 2048 + w * 512);
            gl_lds16(wot + (size_t)(col0 + row) * EMB + k0 + csrc * 8,
                     Bs + s * 2048 + w * 512);
        }
        __syncthreads();
        #pragma unroll
        for (int kk = 0; kk < 2; ++kk) {
            short8 af[4], bf[4];
            #pragma unroll
            for (int mt = 0; mt < 4; ++mt) {
                const int rm = wq * 64 + mt * 16 + l16;
                af[mt] = *(const short8*)(As + rm * 64 + (((kk * 4 + quad) ^ (rm & 7)) * 8));
            }
            #pragma unroll
            for (int nt = 0; nt < 4; ++nt) {
                const int rn = wn * 64 + nt * 16 + l16;
                bf[nt] = *(const short8*)(Bs + rn * 64 + (((kk * 4 + quad) ^ (rn & 7)) * 8));
            }
            #pragma unroll
            for (int mt = 0; mt < 4; ++mt)
                #pragma unroll
                for (int nt = 0; nt < 4; ++nt)
                    acc[mt][nt] = __builtin_amdgcn_mfma_f32_16x16x32_bf16(af[mt], bf[nt], acc[mt][nt], 0, 0, 0);
        }
        __syncthreads();
    }

    #pragma unroll
    for (int nt = 0; nt < 4; ++nt) {
        const int col_g = col0 + wn * 64 + nt * 16 + l16;
        const float bz = bias[col_g];
        #pragma unroll
        for (int mt = 0; mt < 4; ++mt) {
            #pragma unroll
            for (int i = 0; i < 4; ++i) {
                const int row_g = row0 + wq * 64 + mt * 16 + quad * 4 + i;
                out[(size_t)row_g * EMB + col_g] = acc[mt][nt][i] + bz;
            }
        }
    }
}

// ---------------------------------------------------------------------------
extern "C" void kernel_launch(void* const* d_in, const int* in_sizes, int n_in,
                              void* d_out, int out_size, void* d_ws, size_t ws_size,
                              hipStream_t stream) {
    const float* x    = (const float*)d_in[0];
    const void*  mask = d_in[1];
    const float* Wqkv = (const float*)d_in[2];
    const float* bqkv = (const float*)d_in[3];
    const float* Wout = (const float*)d_in[4];
    const float* bout = (const float*)d_in[5];
    float* out = (float*)d_out;

    ushort_t* xb  = (ushort_t*)d_ws;                 // [16384][512]
    ushort_t* wqt = xb + (size_t)MROWS * EMB;        // [1536][512]
    ushort_t* wot = wqt + (size_t)1536 * EMB;        // [512][512]
    ushort_t* qb  = wot + (size_t)EMB * EMB;         // [BH][N][DH]
    ushort_t* kb  = qb + QKV_ELEMS;
    ushort_t* vt  = kb + QKV_ELEMS;                  // [BH][DH][N]
    ushort_t* ab  = vt + QKV_ELEMS;                  // [B][N][EMB]
    float*    pmf = (float*)(ab + (size_t)MROWS * EMB); // f32 [B][SEQ]
    unsigned* pmb = (unsigned*)(pmf + (size_t)BB * SEQ); // u32 [B][SEQ/32]

    prep<<<dim3(PREP_TOTAL), 256, 0, stream>>>(x, mask, Wqkv, Wout, xb, pmf, pmb, wqt, wot);
    qkv_mfma<<<dim3(1536), 256, 0, stream>>>(xb, wqt, bqkv, qb, kb, vt);
    attn_mfma<<<dim3(NBH * (SEQ / 64)), 64, 0, stream>>>(qb, kb, vt, pmf, pmb, ab);
    out_mfma<<<dim3(512), 256, 0, stream>>>(ab, wot, bout, out);
}